// Round 1
// baseline (3278.946 us; speedup 1.0000x reference)
//
#include <hip/hip_runtime.h>
#include <math.h>

// Problem constants
#define BATCH 2
#define NCAM 6
#define DIM 256
#define HEADS 8
#define DH 32
#define HW 2500          // 50*50
#define KP 625           // 25*25 pooled keys per cam
#define NDIM (NCAM*DIM)  // 1536

// ---------------------------------------------------------------------------
// Generic tiled SGEMM: C[M,N] = gather(A)[M,K] @ B[K,N] + bias (+epilogue)
// MODE 0: A plain row-major [M,K]
// MODE 1: QF gather   : row r=(b*6+cam)*2500+hw, col c : q[((b*6+cam)*256+c)*2500+hw]
// MODE 2: ADDQ gather : row r=b*2500+hw, col k=(cam,c) : q[b*3840000+cam*640000+c*2500+hw]
// MODE 3: POOL gather : row r=(b*6+cam)*625+kk, col c  : mean of 2x2 of k/v
// EPI 0: +bias ; EPI 1: +bias then exact GELU ; EPI 2: +bias + res[r*N+col]
// ---------------------------------------------------------------------------
template<int MODE, int EPI>
__global__ __launch_bounds__(256) void gemm_kernel(
    const float* __restrict__ A, const float* __restrict__ B,
    const float* __restrict__ bias, const float* __restrict__ res,
    float* __restrict__ C, int M, int N, int K)
{
    __shared__ float As[16][68];   // +4 pad keeps 16B alignment, kills store conflicts
    __shared__ float Bs[16][64];

    const int tid = threadIdx.x;
    const int nB  = blockIdx.x * 64;
    const int rB  = blockIdx.y * 64;
    const int tx  = tid & 15;      // output col group
    const int ty  = tid >> 4;      // output row group

    float acc[4][4];
#pragma unroll
    for (int i = 0; i < 4; i++)
#pragma unroll
        for (int j = 0; j < 4; j++) acc[i][j] = 0.f;

    for (int kB = 0; kB < K; kB += 16) {
        __syncthreads();
        // ---- load A tile -> As[kk][mm]
        if (MODE == 0) {
            int kk  = tid & 15;
            int mmB = tid >> 4;
#pragma unroll
            for (int p = 0; p < 4; p++) {
                int mm = mmB + p * 16;
                int r  = rB + mm;
                As[kk][mm] = (r < M) ? A[(size_t)r * K + kB + kk] : 0.f;
            }
        } else {
            int mm  = tid & 63;
            int kk0 = tid >> 6;
            int r   = rB + mm;
#pragma unroll
            for (int p = 0; p < 4; p++) {
                int kk = kk0 + 4 * p;
                int k  = kB + kk;
                float v = 0.f;
                if (r < M) {
                    if (MODE == 1) {
                        int slab = r / 2500, hw = r % 2500;
                        v = A[slab * 640000 + k * 2500 + hw];
                    } else if (MODE == 2) {
                        int bb = r / 2500, hw = r % 2500;
                        int cam = k >> 8, c = k & 255;
                        v = A[bb * 3840000 + cam * 640000 + c * 2500 + hw];
                    } else { // POOL
                        int slab = r / 625, kp = r % 625;
                        int i2 = (kp / 25) * 2, j2 = (kp % 25) * 2;
                        const float* p0 = A + (size_t)slab * 640000 + (size_t)k * 2500
                                            + i2 * 50 + j2;
                        v = 0.25f * (p0[0] + p0[1] + p0[50] + p0[51]);
                    }
                }
                As[kk][mm] = v;
            }
        }
        // ---- load B tile -> Bs[kk][nn]   (B row-major K x N, K%16==0, N%64==0)
        {
            int nn = tid & 63, kk0 = tid >> 6;
#pragma unroll
            for (int p = 0; p < 4; p++) {
                int kk = kk0 + 4 * p;
                Bs[kk][nn] = B[(size_t)(kB + kk) * N + nB + nn];
            }
        }
        __syncthreads();
        // ---- micro-kernel 4x4
#pragma unroll
        for (int kk = 0; kk < 16; kk++) {
            float4 a4 = *(const float4*)&As[kk][ty * 4];
            float4 b4 = *(const float4*)&Bs[kk][tx * 4];
            acc[0][0] += a4.x * b4.x; acc[0][1] += a4.x * b4.y;
            acc[0][2] += a4.x * b4.z; acc[0][3] += a4.x * b4.w;
            acc[1][0] += a4.y * b4.x; acc[1][1] += a4.y * b4.y;
            acc[1][2] += a4.y * b4.z; acc[1][3] += a4.y * b4.w;
            acc[2][0] += a4.z * b4.x; acc[2][1] += a4.z * b4.y;
            acc[2][2] += a4.z * b4.z; acc[2][3] += a4.z * b4.w;
            acc[3][0] += a4.w * b4.x; acc[3][1] += a4.w * b4.y;
            acc[3][2] += a4.w * b4.z; acc[3][3] += a4.w * b4.w;
        }
    }
    // ---- epilogue
#pragma unroll
    for (int i = 0; i < 4; i++) {
        int r = rB + ty * 4 + i;
        if (r >= M) continue;
#pragma unroll
        for (int j = 0; j < 4; j++) {
            int col = nB + tx * 4 + j;
            float v = acc[i][j] + bias[col];
            if (EPI == 1) v = 0.5f * v * (1.f + erff(v * 0.70710678118654752f));
            if (EPI == 2) v += res[(size_t)r * N + col];
            C[(size_t)r * N + col] = v;
        }
    }
}

// ---------------------------------------------------------------------------
// Fused attention: joint softmax over (cam,key); unnormalized single pass.
// grid (79, 16) : x = 32-query tile, y = b*8+m.  block 256.
// ---------------------------------------------------------------------------
#define TQ 32
#define CHUNK 64

__global__ __launch_bounds__(256) void attn_kernel(
    const float* __restrict__ qf, const float* __restrict__ kf,
    const float* __restrict__ vf, float* __restrict__ attn_out)
{
    const int qt = blockIdx.x;
    const int bm = blockIdx.y;
    const int b = bm >> 3, m = bm & 7;
    const int q0 = qt * TQ;
    const int tid = threadIdx.x;

    __shared__ float qs[NCAM][TQ][DH];   // 24 KB
    __shared__ float ks[CHUNK][DH];      // 8 KB
    __shared__ float vs[CHUNK][DH];      // 8 KB
    __shared__ float ps[TQ][CHUNK];      // 8 KB
    __shared__ float zred[TQ][8];
    __shared__ float Zs[TQ];

    // load query tile (all cams, this head)
    for (int idx = tid; idx < NCAM * TQ * DH; idx += 256) {
        int n = idx >> 10;           // /(TQ*DH)
        int q = (idx >> 5) & 31;
        int dh = idx & 31;
        float v = 0.f;
        if (q0 + q < HW)
            v = qf[(((size_t)(b * 6 + n) * HW) + q0 + q) * DIM + m * DH + dh];
        qs[n][q][dh] = v;
    }
    if (tid < TQ) Zs[tid] = 0.f;

    float acc[NCAM][4];
#pragma unroll
    for (int n = 0; n < NCAM; n++)
#pragma unroll
        for (int i = 0; i < 4; i++) acc[n][i] = 0.f;

    const float scale = 0.17677669529663687f;   // 1/sqrt(32)

#pragma unroll
    for (int cam = 0; cam < NCAM; cam++) {
        const float* kbase = kf + (size_t)(b * 6 + cam) * KP * DIM + m * DH;
        const float* vbase = vf + (size_t)(b * 6 + cam) * KP * DIM + m * DH;
        for (int c0 = 0; c0 < KP; c0 += CHUNK) {
            const int nk = min(CHUNK, KP - c0);
            __syncthreads();   // protect ks/vs/ps/zred from previous chunk
            // stage K/V chunk
            for (int l = 0; l < CHUNK * DH / 256; l++) {
                int idx = tid + l * 256;
                int j = idx >> 5, dh = idx & 31;
                float kv = 0.f, vv = 0.f;
                if (j < nk) {
                    kv = kbase[(size_t)(c0 + j) * DIM + dh];
                    vv = vbase[(size_t)(c0 + j) * DIM + dh];
                }
                ks[j][dh] = kv; vs[j][dh] = vv;
            }
            __syncthreads();
            // S phase: thread -> (2 queries, 4 keys)
            {
                int qp = tid >> 4, kg = tid & 15;
                int qa = qp * 2;
                int j0 = kg * 4;
                float s0[4] = {0, 0, 0, 0}, s1[4] = {0, 0, 0, 0};
#pragma unroll
                for (int d4 = 0; d4 < DH; d4 += 4) {
                    float4 A0 = *(const float4*)&qs[cam][qa][d4];
                    float4 A1 = *(const float4*)&qs[cam][qa + 1][d4];
#pragma unroll
                    for (int jj = 0; jj < 4; jj++) {
                        float4 kv = *(const float4*)&ks[j0 + jj][d4];
                        s0[jj] += A0.x * kv.x + A0.y * kv.y + A0.z * kv.z + A0.w * kv.w;
                        s1[jj] += A1.x * kv.x + A1.y * kv.y + A1.z * kv.z + A1.w * kv.w;
                    }
                }
#pragma unroll
                for (int jj = 0; jj < 4; jj++) {
                    int j = j0 + jj;
                    ps[qa][j]     = (j < nk) ? expf(scale * s0[jj]) : 0.f;
                    ps[qa + 1][j] = (j < nk) ? expf(scale * s1[jj]) : 0.f;
                }
            }
            __syncthreads();
            // Z partials + P phase (both read ps, disjoint writes)
            {
                int q = tid >> 3, seg = tid & 7;
                float s = 0.f;
#pragma unroll
                for (int j = 0; j < 8; j++) s += ps[q][seg * 8 + j];
                zred[q][seg] = s;
            }
            {
                int q = tid >> 3;
                int dh0 = (tid & 7) << 2;
                for (int j = 0; j < CHUNK; j += 4) {
                    float4 p4 = *(const float4*)&ps[q][j];
                    float4 v0 = *(const float4*)&vs[j + 0][dh0];
                    float4 v1 = *(const float4*)&vs[j + 1][dh0];
                    float4 v2 = *(const float4*)&vs[j + 2][dh0];
                    float4 v3 = *(const float4*)&vs[j + 3][dh0];
                    acc[cam][0] += p4.x * v0.x + p4.y * v1.x + p4.z * v2.x + p4.w * v3.x;
                    acc[cam][1] += p4.x * v0.y + p4.y * v1.y + p4.z * v2.y + p4.w * v3.y;
                    acc[cam][2] += p4.x * v0.z + p4.y * v1.z + p4.z * v2.z + p4.w * v3.z;
                    acc[cam][3] += p4.x * v0.w + p4.y * v1.w + p4.z * v2.w + p4.w * v3.w;
                }
            }
            __syncthreads();
            if (tid < TQ) {
                float z = 0.f;
#pragma unroll
                for (int s = 0; s < 8; s++) z += zred[tid][s];
                Zs[tid] += z;
            }
        }
    }
    __syncthreads();
    // write out: attn_out[(b*2500+q), cam*256 + m*32 + dh]
    {
        int q = tid >> 3;
        int dh0 = (tid & 7) << 2;
        if (q0 + q < HW) {
            float invZ = 1.f / Zs[q];
            size_t rowbase = ((size_t)b * HW + q0 + q) * NDIM;
#pragma unroll
            for (int n = 0; n < NCAM; n++)
#pragma unroll
                for (int i = 0; i < 4; i++)
                    attn_out[rowbase + n * DIM + m * DH + dh0 + i] = acc[n][i] * invZ;
        }
    }
}

// ---------------------------------------------------------------------------
// LayerNorm over 1536, in place. grid 5000, block 256.
// ---------------------------------------------------------------------------
__global__ __launch_bounds__(256) void ln_pre_kernel(
    float* __restrict__ x, const float* __restrict__ g, const float* __restrict__ bt)
{
    const int row = blockIdx.x;
    const int tid = threadIdx.x;
    float* p = x + (size_t)row * NDIM;
    float v[6];
    float s = 0.f, ss = 0.f;
#pragma unroll
    for (int i = 0; i < 6; i++) {
        v[i] = p[tid + i * 256];
        s += v[i]; ss += v[i] * v[i];
    }
    __shared__ float rs[4], rss[4];
    int lane = tid & 63, wid = tid >> 6;
#pragma unroll
    for (int o = 32; o > 0; o >>= 1) { s += __shfl_down(s, o); ss += __shfl_down(ss, o); }
    if (lane == 0) { rs[wid] = s; rss[wid] = ss; }
    __syncthreads();
    s = rs[0] + rs[1] + rs[2] + rs[3];
    ss = rss[0] + rss[1] + rss[2] + rss[3];
    float mu = s * (1.f / NDIM);
    float var = ss * (1.f / NDIM) - mu * mu;
    float inv = rsqrtf(var + 1e-5f);
#pragma unroll
    for (int i = 0; i < 6; i++) {
        int c = tid + i * 256;
        p[c] = (v[i] - mu) * inv * g[c] + bt[c];
    }
}

// ---------------------------------------------------------------------------
// Final: out[b,c,hw] = x[row,c] + LN256(y2[row]) * g + b.  grid 5000, block 256.
// ---------------------------------------------------------------------------
__global__ __launch_bounds__(256) void final_kernel(
    const float* __restrict__ x, const float* __restrict__ y2,
    const float* __restrict__ g, const float* __restrict__ bt,
    float* __restrict__ out)
{
    const int row = blockIdx.x;
    const int tid = threadIdx.x;
    float v = y2[(size_t)row * DIM + tid];
    float s = v, ss = v * v;
    __shared__ float rs[4], rss[4];
    int lane = tid & 63, wid = tid >> 6;
#pragma unroll
    for (int o = 32; o > 0; o >>= 1) { s += __shfl_down(s, o); ss += __shfl_down(ss, o); }
    if (lane == 0) { rs[wid] = s; rss[wid] = ss; }
    __syncthreads();
    s = rs[0] + rs[1] + rs[2] + rs[3];
    ss = rss[0] + rss[1] + rss[2] + rss[3];
    float mu = s * (1.f / DIM);
    float var = ss * (1.f / DIM) - mu * mu;
    float inv = rsqrtf(var + 1e-5f);
    float r = x[(size_t)row * DIM + tid] + (v - mu) * inv * g[tid] + bt[tid];
    int b = row / 2500, hw = row % 2500;
    out[(size_t)b * 640000 + (size_t)tid * 2500 + hw] = r;
}

// ---------------------------------------------------------------------------
extern "C" void kernel_launch(void* const* d_in, const int* in_sizes, int n_in,
                              void* d_out, int out_size, void* d_ws, size_t ws_size,
                              hipStream_t stream)
{
    const float* q     = (const float*)d_in[0];
    const float* k     = (const float*)d_in[1];
    const float* v     = (const float*)d_in[2];
    const float* Wq    = (const float*)d_in[3];
    const float* bq    = (const float*)d_in[4];
    const float* Wk    = (const float*)d_in[5];
    const float* bk    = (const float*)d_in[6];
    const float* Wv    = (const float*)d_in[7];
    const float* bv    = (const float*)d_in[8];
    const float* Wproj = (const float*)d_in[9];
    const float* bproj = (const float*)d_in[10];
    const float* Waddq = (const float*)d_in[11];
    const float* baddq = (const float*)d_in[12];
    const float* W1    = (const float*)d_in[13];
    const float* b1    = (const float*)d_in[14];
    const float* W2    = (const float*)d_in[15];
    const float* b2    = (const float*)d_in[16];
    const float* g_pre = (const float*)d_in[17];
    const float* b_pre = (const float*)d_in[18];
    const float* g_nrm = (const float*)d_in[19];
    const float* b_nrm = (const float*)d_in[20];
    float* out = (float*)d_out;

    // workspace layout (floats)
    float* ws = (float*)d_ws;
    float* qf       = ws;                    // 7,680,000
    float* kf       = qf + 7680000;          // 1,920,000
    float* vfb      = kf + 1920000;          // 1,920,000
    float* add_q    = vfb + 1920000;         // 1,280,000
    float* attn_out = add_q + 1280000;       // 7,680,000
    float* x        = attn_out + 7680000;    // 1,280,000
    float* h1       = x + 1280000;           // 2,560,000
    float* y2       = h1 + 2560000;          // 1,280,000

    dim3 blk(256);

    // qf = gatherT(q) @ Wq + bq     (30000 x 256, K=256)
    gemm_kernel<1, 0><<<dim3(4, 469), blk, 0, stream>>>(q, Wq, bq, nullptr, qf, 30000, 256, 256);
    // kf = pool(k) @ Wk + bk        (7500 x 256, K=256)
    gemm_kernel<3, 0><<<dim3(4, 118), blk, 0, stream>>>(k, Wk, bk, nullptr, kf, 7500, 256, 256);
    // vf = pool(v) @ Wv + bv
    gemm_kernel<3, 0><<<dim3(4, 118), blk, 0, stream>>>(v, Wv, bv, nullptr, vfb, 7500, 256, 256);
    // add_q = gather(q) @ Waddq + baddq   (5000 x 256, K=1536)
    gemm_kernel<2, 0><<<dim3(4, 79), blk, 0, stream>>>(q, Waddq, baddq, nullptr, add_q, 5000, 256, 1536);
    // attention
    attn_kernel<<<dim3(79, 16), blk, 0, stream>>>(qf, kf, vfb, attn_out);
    // pre-LN over 1536 (in place)
    ln_pre_kernel<<<dim3(5000), blk, 0, stream>>>(attn_out, g_pre, b_pre);
    // x = ln(attn_out) @ Wproj + bproj + add_q
    gemm_kernel<0, 2><<<dim3(4, 79), blk, 0, stream>>>(attn_out, Wproj, bproj, add_q, x, 5000, 256, 1536);
    // h1 = gelu(x @ W1 + b1)        (5000 x 512, K=256)
    gemm_kernel<0, 1><<<dim3(8, 79), blk, 0, stream>>>(x, W1, b1, nullptr, h1, 5000, 512, 256);
    // y2 = h1 @ W2 + b2             (5000 x 256, K=512)
    gemm_kernel<0, 0><<<dim3(4, 79), blk, 0, stream>>>(h1, W2, b2, nullptr, y2, 5000, 256, 512);
    // out = transpose(x + LN256(y2))
    final_kernel<<<dim3(5000), blk, 0, stream>>>(x, y2, g_nrm, b_nrm, out);
}

// Round 2
// 1100.570 us; speedup vs baseline: 2.9793x; 2.9793x over previous
//
#include <hip/hip_runtime.h>
#include <math.h>

// Problem constants
#define BATCH 2
#define NCAM 6
#define DIM 256
#define HEADS 8
#define DH 32
#define HW 2500          // 50*50
#define KP 625           // 25*25 pooled keys per cam
#define NDIM (NCAM*DIM)  // 1536

// ---------------------------------------------------------------------------
// Generic tiled SGEMM: C[M,N] = gather(A)[M,K] @ B[K,N] + bias (+epilogue)
// MODE 0: A plain row-major [M,K]
// MODE 1: QF gather   : row r=(b*6+cam)*2500+hw, col c : q[((b*6+cam)*256+c)*2500+hw]
// MODE 2: ADDQ gather : row r=b*2500+hw, col k=(cam,c) : q[b*3840000+cam*640000+c*2500+hw]
// MODE 3: POOL gather : row r=(b*6+cam)*625+kk, col c  : mean of 2x2 of k/v
// EPI 0: +bias ; EPI 1: +bias then exact GELU ; EPI 2: +bias + res[r*N+col]
// ---------------------------------------------------------------------------
template<int MODE, int EPI>
__global__ __launch_bounds__(256) void gemm_kernel(
    const float* __restrict__ A, const float* __restrict__ B,
    const float* __restrict__ bias, const float* __restrict__ res,
    float* __restrict__ C, int M, int N, int K)
{
    __shared__ float As[16][68];
    __shared__ float Bs[16][64];

    const int tid = threadIdx.x;
    const int nB  = blockIdx.x * 64;
    const int rB  = blockIdx.y * 64;
    const int tx  = tid & 15;
    const int ty  = tid >> 4;

    float acc[4][4];
#pragma unroll
    for (int i = 0; i < 4; i++)
#pragma unroll
        for (int j = 0; j < 4; j++) acc[i][j] = 0.f;

    for (int kB = 0; kB < K; kB += 16) {
        __syncthreads();
        if (MODE == 0) {
            int kk  = tid & 15;
            int mmB = tid >> 4;
#pragma unroll
            for (int p = 0; p < 4; p++) {
                int mm = mmB + p * 16;
                int r  = rB + mm;
                As[kk][mm] = (r < M) ? A[(size_t)r * K + kB + kk] : 0.f;
            }
        } else {
            int mm  = tid & 63;
            int kk0 = tid >> 6;
            int r   = rB + mm;
#pragma unroll
            for (int p = 0; p < 4; p++) {
                int kk = kk0 + 4 * p;
                int k  = kB + kk;
                float v = 0.f;
                if (r < M) {
                    if (MODE == 1) {
                        int slab = r / 2500, hw = r % 2500;
                        v = A[slab * 640000 + k * 2500 + hw];
                    } else if (MODE == 2) {
                        int bb = r / 2500, hw = r % 2500;
                        int cam = k >> 8, c = k & 255;
                        v = A[bb * 3840000 + cam * 640000 + c * 2500 + hw];
                    } else {
                        int slab = r / 625, kp = r % 625;
                        int i2 = (kp / 25) * 2, j2 = (kp % 25) * 2;
                        const float* p0 = A + (size_t)slab * 640000 + (size_t)k * 2500
                                            + i2 * 50 + j2;
                        v = 0.25f * (p0[0] + p0[1] + p0[50] + p0[51]);
                    }
                }
                As[kk][mm] = v;
            }
        }
        {
            int nn = tid & 63, kk0 = tid >> 6;
#pragma unroll
            for (int p = 0; p < 4; p++) {
                int kk = kk0 + 4 * p;
                Bs[kk][nn] = B[(size_t)(kB + kk) * N + nB + nn];
            }
        }
        __syncthreads();
#pragma unroll
        for (int kk = 0; kk < 16; kk++) {
            float4 a4 = *(const float4*)&As[kk][ty * 4];
            float4 b4 = *(const float4*)&Bs[kk][tx * 4];
            acc[0][0] += a4.x * b4.x; acc[0][1] += a4.x * b4.y;
            acc[0][2] += a4.x * b4.z; acc[0][3] += a4.x * b4.w;
            acc[1][0] += a4.y * b4.x; acc[1][1] += a4.y * b4.y;
            acc[1][2] += a4.y * b4.z; acc[1][3] += a4.y * b4.w;
            acc[2][0] += a4.z * b4.x; acc[2][1] += a4.z * b4.y;
            acc[2][2] += a4.z * b4.z; acc[2][3] += a4.z * b4.w;
            acc[3][0] += a4.w * b4.x; acc[3][1] += a4.w * b4.y;
            acc[3][2] += a4.w * b4.z; acc[3][3] += a4.w * b4.w;
        }
    }
#pragma unroll
    for (int i = 0; i < 4; i++) {
        int r = rB + ty * 4 + i;
        if (r >= M) continue;
#pragma unroll
        for (int j = 0; j < 4; j++) {
            int col = nB + tx * 4 + j;
            float v = acc[i][j] + bias[col];
            if (EPI == 1) v = 0.5f * v * (1.f + erff(v * 0.70710678118654752f));
            if (EPI == 2) v += res[(size_t)r * N + col];
            C[(size_t)r * N + col] = v;
        }
    }
}

// ---------------------------------------------------------------------------
// Fused attention v2 — per-camera blocks, conflict-free LDS, unnormalized
// accumulate + Z partials (joint softmax normalization fused into ln_pre).
// grid (79, 16, 6): x = 32-query tile, y = b*8+m, z = cam. block 256.
//
// LDS layouts (all conflict-free per bank arithmetic):
//   qs [32][33] : scalar reads, bank (q+d)%32, 4 distinct rows/wave -> free
//   kst[32][68] : K transposed [d][j]; float4 reads at bank-quad (4d+4kg)%32
//                 -> 16 distinct 16B addrs covering 8 quads x2 -> ~2cyc
//   vs [64][32] : reads broadcast across q (8 distinct 16B addrs) -> free
//   ps [32][68] : written as float4/thread (64 distinct, even banks);
//                 read scalar broadcast (8 distinct rows) -> free
// ---------------------------------------------------------------------------
#define TQ 32
#define CHUNK 64

__global__ __launch_bounds__(256) void attn_kernel(
    const float* __restrict__ qf, const float* __restrict__ kf,
    const float* __restrict__ vf, float* __restrict__ attn_out,
    float* __restrict__ Zp)
{
    const int qt  = blockIdx.x;
    const int bm  = blockIdx.y;
    const int cam = blockIdx.z;
    const int b = bm >> 3, m = bm & 7;
    const int q0 = qt * TQ;
    const int tid = threadIdx.x;

    __shared__ __align__(16) float qs[TQ][DH + 1];
    __shared__ __align__(16) float kst[DH][CHUNK + 4];
    __shared__ __align__(16) float vs[CHUNK][DH];
    __shared__ __align__(16) float ps[TQ][CHUNK + 4];

    // load query tile (this cam, this head)
    for (int idx = tid; idx < TQ * DH; idx += 256) {
        int q = idx >> 5, d = idx & 31;
        float v = 0.f;
        if (q0 + q < HW)
            v = qf[(((size_t)(b * 6 + cam) * HW) + q0 + q) * DIM + m * DH + d];
        qs[q][d] = v;
    }

    const float* kbase = kf + (size_t)(b * 6 + cam) * KP * DIM + m * DH;
    const float* vbase = vf + (size_t)(b * 6 + cam) * KP * DIM + m * DH;

    float acc[4] = {0.f, 0.f, 0.f, 0.f};
    float zacc = 0.f;
    const float scale = 0.17677669529663687f;   // 1/sqrt(32)

    const int qp = tid >> 4, kg = tid & 15;     // S-phase mapping
    const int qa = qp * 2,  j0 = kg * 4;
    const int qq = tid >> 3;                    // P-phase mapping
    const int dh0 = (tid & 7) << 2;

    for (int c0 = 0; c0 < KP; c0 += CHUNK) {
        const int nk = min(CHUNK, KP - c0);
        __syncthreads();   // previous chunk's P-phase done with kst/vs/ps
        // ---- stage K (transposed) and V; float4 global loads
        for (int l = 0; l < 2; l++) {
            int idx = tid + l * 256;            // over 512 float4 slots
            int j = idx >> 3, d4 = (idx & 7) << 2;
            float4 kv = {0, 0, 0, 0}, vv = {0, 0, 0, 0};
            if (j < nk) {
                kv = *(const float4*)&kbase[(size_t)(c0 + j) * DIM + d4];
                vv = *(const float4*)&vbase[(size_t)(c0 + j) * DIM + d4];
            }
            kst[d4 + 0][j] = kv.x; kst[d4 + 1][j] = kv.y;
            kst[d4 + 2][j] = kv.z; kst[d4 + 3][j] = kv.w;
            *(float4*)&vs[j][d4] = vv;
        }
        __syncthreads();
        // ---- S phase: thread -> (2 queries, 4 keys), exp, float4 -> ps
        {
            float s0[4] = {0, 0, 0, 0}, s1[4] = {0, 0, 0, 0};
#pragma unroll
            for (int d = 0; d < DH; d++) {
                float a0 = qs[qa][d];
                float a1 = qs[qa + 1][d];
                float4 k4 = *(const float4*)&kst[d][j0];
                s0[0] += a0 * k4.x; s0[1] += a0 * k4.y;
                s0[2] += a0 * k4.z; s0[3] += a0 * k4.w;
                s1[0] += a1 * k4.x; s1[1] += a1 * k4.y;
                s1[2] += a1 * k4.z; s1[3] += a1 * k4.w;
            }
            float4 e0, e1;
            e0.x = (j0 + 0 < nk) ? __expf(scale * s0[0]) : 0.f;
            e0.y = (j0 + 1 < nk) ? __expf(scale * s0[1]) : 0.f;
            e0.z = (j0 + 2 < nk) ? __expf(scale * s0[2]) : 0.f;
            e0.w = (j0 + 3 < nk) ? __expf(scale * s0[3]) : 0.f;
            e1.x = (j0 + 0 < nk) ? __expf(scale * s1[0]) : 0.f;
            e1.y = (j0 + 1 < nk) ? __expf(scale * s1[1]) : 0.f;
            e1.z = (j0 + 2 < nk) ? __expf(scale * s1[2]) : 0.f;
            e1.w = (j0 + 3 < nk) ? __expf(scale * s1[3]) : 0.f;
            *(float4*)&ps[qa][j0]     = e0;
            *(float4*)&ps[qa + 1][j0] = e1;
        }
        __syncthreads();
        // ---- P phase: outer product over keys; Z folded in (broadcast reads)
#pragma unroll 8
        for (int j = 0; j < CHUNK; j++) {
            float p = ps[qq][j];
            float4 v4 = *(const float4*)&vs[j][dh0];
            zacc += p;
            acc[0] += p * v4.x; acc[1] += p * v4.y;
            acc[2] += p * v4.z; acc[3] += p * v4.w;
        }
    }
    // ---- epilogue: unnormalized output + Z partial
    if (q0 + qq < HW) {
        size_t rowbase = ((size_t)b * HW + q0 + qq) * NDIM + cam * DIM + m * DH + dh0;
        float4 o; o.x = acc[0]; o.y = acc[1]; o.z = acc[2]; o.w = acc[3];
        *(float4*)&attn_out[rowbase] = o;
        if ((tid & 7) == 0)
            Zp[((size_t)(b * 8 + m) * 6 + cam) * HW + q0 + qq] = zacc;
    }
}

// ---------------------------------------------------------------------------
// LayerNorm over 1536 with fused joint-softmax normalization, in place.
// grid 5000, block 256.
// ---------------------------------------------------------------------------
__global__ __launch_bounds__(256) void ln_pre_kernel(
    float* __restrict__ x, const float* __restrict__ Zp,
    const float* __restrict__ g, const float* __restrict__ bt)
{
    const int row = blockIdx.x;
    const int tid = threadIdx.x;
    const int b = row / 2500, q = row % 2500;
    __shared__ float zinv[8];
    if (tid < 8) {
        float z = 0.f;
#pragma unroll
        for (int cam = 0; cam < 6; cam++)
            z += Zp[((size_t)(b * 8 + tid) * 6 + cam) * HW + q];
        zinv[tid] = 1.f / z;
    }
    __syncthreads();
    float* p = x + (size_t)row * NDIM;
    float v[6];
    float s = 0.f, ss = 0.f;
#pragma unroll
    for (int i = 0; i < 6; i++) {
        int c = tid + i * 256;
        v[i] = p[c] * zinv[(c >> 5) & 7];
        s += v[i]; ss += v[i] * v[i];
    }
    __shared__ float rs[4], rss[4];
    int lane = tid & 63, wid = tid >> 6;
#pragma unroll
    for (int o = 32; o > 0; o >>= 1) { s += __shfl_down(s, o); ss += __shfl_down(ss, o); }
    if (lane == 0) { rs[wid] = s; rss[wid] = ss; }
    __syncthreads();
    s = rs[0] + rs[1] + rs[2] + rs[3];
    ss = rss[0] + rss[1] + rss[2] + rss[3];
    float mu = s * (1.f / NDIM);
    float var = ss * (1.f / NDIM) - mu * mu;
    float inv = rsqrtf(var + 1e-5f);
#pragma unroll
    for (int i = 0; i < 6; i++) {
        int c = tid + i * 256;
        p[c] = (v[i] - mu) * inv * g[c] + bt[c];
    }
}

// ---------------------------------------------------------------------------
// Final: out[b,c,hw] = x[row,c] + LN256(y2[row]) * g + b.  grid 5000, block 256.
// ---------------------------------------------------------------------------
__global__ __launch_bounds__(256) void final_kernel(
    const float* __restrict__ x, const float* __restrict__ y2,
    const float* __restrict__ g, const float* __restrict__ bt,
    float* __restrict__ out)
{
    const int row = blockIdx.x;
    const int tid = threadIdx.x;
    float v = y2[(size_t)row * DIM + tid];
    float s = v, ss = v * v;
    __shared__ float rs[4], rss[4];
    int lane = tid & 63, wid = tid >> 6;
#pragma unroll
    for (int o = 32; o > 0; o >>= 1) { s += __shfl_down(s, o); ss += __shfl_down(ss, o); }
    if (lane == 0) { rs[wid] = s; rss[wid] = ss; }
    __syncthreads();
    s = rs[0] + rs[1] + rs[2] + rs[3];
    ss = rss[0] + rss[1] + rss[2] + rss[3];
    float mu = s * (1.f / DIM);
    float var = ss * (1.f / DIM) - mu * mu;
    float inv = rsqrtf(var + 1e-5f);
    float r = x[(size_t)row * DIM + tid] + (v - mu) * inv * g[tid] + bt[tid];
    int b = row / 2500, hw = row % 2500;
    out[(size_t)b * 640000 + (size_t)tid * 2500 + hw] = r;
}

// ---------------------------------------------------------------------------
extern "C" void kernel_launch(void* const* d_in, const int* in_sizes, int n_in,
                              void* d_out, int out_size, void* d_ws, size_t ws_size,
                              hipStream_t stream)
{
    const float* q     = (const float*)d_in[0];
    const float* k     = (const float*)d_in[1];
    const float* v     = (const float*)d_in[2];
    const float* Wq    = (const float*)d_in[3];
    const float* bq    = (const float*)d_in[4];
    const float* Wk    = (const float*)d_in[5];
    const float* bk    = (const float*)d_in[6];
    const float* Wv    = (const float*)d_in[7];
    const float* bv    = (const float*)d_in[8];
    const float* Wproj = (const float*)d_in[9];
    const float* bproj = (const float*)d_in[10];
    const float* Waddq = (const float*)d_in[11];
    const float* baddq = (const float*)d_in[12];
    const float* W1    = (const float*)d_in[13];
    const float* b1    = (const float*)d_in[14];
    const float* W2    = (const float*)d_in[15];
    const float* b2    = (const float*)d_in[16];
    const float* g_pre = (const float*)d_in[17];
    const float* b_pre = (const float*)d_in[18];
    const float* g_nrm = (const float*)d_in[19];
    const float* b_nrm = (const float*)d_in[20];
    float* out = (float*)d_out;

    // workspace layout (floats)
    float* ws = (float*)d_ws;
    float* qf       = ws;                    // 7,680,000
    float* kf       = qf + 7680000;          // 1,920,000
    float* vfb      = kf + 1920000;          // 1,920,000
    float* add_q    = vfb + 1920000;         // 1,280,000
    float* attn_out = add_q + 1280000;       // 7,680,000
    float* x        = attn_out + 7680000;    // 1,280,000
    float* h1       = x + 1280000;           // 2,560,000
    float* y2       = h1 + 2560000;          // 1,280,000
    // Z partials (240,000 floats) alias h1: written by attn, consumed by
    // ln_pre, both strictly before the h1 GEMM in stream order.
    float* Zp       = h1;

    dim3 blk(256);

    gemm_kernel<1, 0><<<dim3(4, 469), blk, 0, stream>>>(q, Wq, bq, nullptr, qf, 30000, 256, 256);
    gemm_kernel<3, 0><<<dim3(4, 118), blk, 0, stream>>>(k, Wk, bk, nullptr, kf, 7500, 256, 256);
    gemm_kernel<3, 0><<<dim3(4, 118), blk, 0, stream>>>(v, Wv, bv, nullptr, vfb, 7500, 256, 256);
    gemm_kernel<2, 0><<<dim3(4, 79), blk, 0, stream>>>(q, Waddq, baddq, nullptr, add_q, 5000, 256, 1536);
    attn_kernel<<<dim3(79, 16, 6), blk, 0, stream>>>(qf, kf, vfb, attn_out, Zp);
    ln_pre_kernel<<<dim3(5000), blk, 0, stream>>>(attn_out, Zp, g_pre, b_pre);
    gemm_kernel<0, 2><<<dim3(4, 79), blk, 0, stream>>>(attn_out, Wproj, bproj, add_q, x, 5000, 256, 1536);
    gemm_kernel<0, 1><<<dim3(8, 79), blk, 0, stream>>>(x, W1, b1, nullptr, h1, 5000, 512, 256);
    gemm_kernel<0, 0><<<dim3(4, 79), blk, 0, stream>>>(h1, W2, b2, nullptr, y2, 5000, 256, 512);
    final_kernel<<<dim3(5000), blk, 0, stream>>>(x, y2, g_nrm, b_nrm, out);
}

// Round 3
// 774.481 us; speedup vs baseline: 4.2337x; 1.4210x over previous
//
#include <hip/hip_runtime.h>
#include <math.h>

// Problem constants
#define BATCH 2
#define NCAM 6
#define DIM 256
#define HEADS 8
#define DH 32
#define HW 2500          // 50*50
#define KP 625           // 25*25 pooled keys per cam
#define NDIM (NCAM*DIM)  // 1536

typedef __attribute__((ext_vector_type(8))) short short8;
typedef __attribute__((ext_vector_type(4))) float f32x4;

__device__ __forceinline__ short f2bf(float f) {
    union { float f; unsigned u; } v; v.f = f;
    unsigned r = v.u + 0x7fffu + ((v.u >> 16) & 1u);   // round-to-nearest-even
    return (short)(r >> 16);
}

// ---------------------------------------------------------------------------
// Weight transpose+convert: Wt[n*K+k] = bf16(W[k*N+n]).  32x32 LDS tiles.
// Up to 4 jobs per launch (struct by value).
// ---------------------------------------------------------------------------
struct WtJob { const float* src; short* dst; int K, N; };
struct WtArgs { WtJob j[4]; };

__global__ __launch_bounds__(256) void wtconv(WtArgs args) {
    WtJob jb = args.j[blockIdx.z];
    int nB = blockIdx.x * 32, kB = blockIdx.y * 32;
    if (nB >= jb.N || kB >= jb.K) return;
    __shared__ float t[32][33];
    int tx = threadIdx.x & 31, ty = threadIdx.x >> 5;   // ty 0..7
#pragma unroll
    for (int i = 0; i < 32; i += 8)
        t[ty + i][tx] = jb.src[(size_t)(kB + ty + i) * jb.N + nB + tx];
    __syncthreads();
#pragma unroll
    for (int i = 0; i < 32; i += 8)
        jb.dst[(size_t)(nB + ty + i) * jb.K + kB + tx] = f2bf(t[tx][ty + i]);
}

// ---------------------------------------------------------------------------
// bf16 MFMA GEMM: C[M,N] = gather(A)[M,K] @ Bt^T + bias (+epilogue), fp32 acc.
// Bt is pre-transposed bf16 weights [N][K].
// Tile: BM=128, BN=64, BK=32. Block 256 (4 waves); wave w owns rows w*32..+32.
// MFMA 16x16x32_bf16: A-frag lane(m=lane&15, k=quad*8+j); B-frag symmetric
// (n=lane&15); C/D col=lane&15, row=quad*4+reg (guide §3, m89-verified).
// LDS rows are 64 B (32 bf16); 16B-group swizzle g_phys = g ^ (row&3) keeps
// b128 reads/writes at <=2-way bank aliasing (free per m136).
// MODE 0: A row-major [M,K]
// MODE 1: QF gather    A[slab*640000 + k*2500 + hw],     r = slab*2500+hw
// MODE 2: ADDQ gather  A[b*3840000+cam*640000+c*2500+hw], k=(cam<<8)|c
// MODE 3: POOL gather  mean 2x2                           r = slab*625+kp
// EPI 0: +bias ; 1: +bias,GELU ; 2: +bias + res[r*N+col]
// ---------------------------------------------------------------------------
template<int MODE, int EPI>
__global__ __launch_bounds__(256) void mgemm(
    const float* __restrict__ A, const short* __restrict__ Bt,
    const float* __restrict__ bias, const float* __restrict__ res,
    float* __restrict__ C, int M, int N, int K)
{
    __shared__ short As[128 * 32];
    __shared__ short Bs[64 * 32];

    const int tid  = threadIdx.x;
    const int nB   = blockIdx.x * 64;
    const int rB   = blockIdx.y * 128;
    const int w    = tid >> 6;
    const int lane = tid & 63;
    const int l15  = lane & 15;
    const int quad = lane >> 4;

    f32x4 acc[2][4];
#pragma unroll
    for (int i = 0; i < 2; i++)
#pragma unroll
        for (int jt = 0; jt < 4; jt++) acc[i][jt] = (f32x4){0.f, 0.f, 0.f, 0.f};

    for (int kB = 0; kB < K; kB += 32) {
        __syncthreads();
        // ---- stage A (fp32 -> bf16)
        if (MODE == 0) {
            int r = tid >> 1, k0 = (tid & 1) * 16;
            int rg = rB + r;
            short tmp[16];
            if (rg < M) {
                const float* p = &A[(size_t)rg * K + kB + k0];
#pragma unroll
                for (int j = 0; j < 16; j += 4) {
                    float4 f = *(const float4*)&p[j];
                    tmp[j] = f2bf(f.x); tmp[j + 1] = f2bf(f.y);
                    tmp[j + 2] = f2bf(f.z); tmp[j + 3] = f2bf(f.w);
                }
            } else {
#pragma unroll
                for (int j = 0; j < 16; j++) tmp[j] = 0;
            }
            int g0 = k0 >> 3;
            *(short8*)&As[r * 32 + ((g0 ^ (r & 3)) << 3)]       = *(short8*)&tmp[0];
            *(short8*)&As[r * 32 + (((g0 + 1) ^ (r & 3)) << 3)] = *(short8*)&tmp[8];
        } else {
            int r = tid & 127, k0 = (tid >> 7) * 16;
            int rg = rB + r;
            short tmp[16];
            if (rg < M) {
                if (MODE == 1) {
                    int slab = rg / 2500, hw = rg % 2500;
                    const float* p = A + (size_t)slab * 640000 + hw;
#pragma unroll
                    for (int j = 0; j < 16; j++)
                        tmp[j] = f2bf(p[(size_t)(kB + k0 + j) * 2500]);
                } else if (MODE == 2) {
                    int bb = rg / 2500, hw = rg % 2500;
#pragma unroll
                    for (int j = 0; j < 16; j++) {
                        int kk = kB + k0 + j;
                        int cam = kk >> 8, c = kk & 255;
                        tmp[j] = f2bf(A[(size_t)bb * 3840000 + cam * 640000 + c * 2500 + hw]);
                    }
                } else { // POOL
                    int slab = rg / 625, kp = rg % 625;
                    int i2 = (kp / 25) * 2, j2 = (kp % 25) * 2;
                    const float* p = A + (size_t)slab * 640000 + i2 * 50 + j2;
#pragma unroll
                    for (int j = 0; j < 16; j++) {
                        const float* p0 = p + (size_t)(kB + k0 + j) * 2500;
                        tmp[j] = f2bf(0.25f * (p0[0] + p0[1] + p0[50] + p0[51]));
                    }
                }
            } else {
#pragma unroll
                for (int j = 0; j < 16; j++) tmp[j] = 0;
            }
            int g0 = k0 >> 3;
            *(short8*)&As[r * 32 + ((g0 ^ (r & 3)) << 3)]       = *(short8*)&tmp[0];
            *(short8*)&As[r * 32 + (((g0 + 1) ^ (r & 3)) << 3)] = *(short8*)&tmp[8];
        }
        // ---- stage B (already bf16, [N][K] rows)
        {
            int n = tid >> 2, gk = tid & 3;
            short8 bv = *(const short8*)&Bt[(size_t)(nB + n) * K + kB + gk * 8];
            *(short8*)&Bs[n * 32 + ((gk ^ (n & 3)) << 3)] = bv;
        }
        __syncthreads();
        // ---- fragments + MFMA
        short8 af[2], bfr[4];
#pragma unroll
        for (int i = 0; i < 2; i++) {
            int m = w * 32 + i * 16 + l15;
            af[i] = *(const short8*)&As[m * 32 + ((quad ^ (m & 3)) << 3)];
        }
#pragma unroll
        for (int jt = 0; jt < 4; jt++) {
            int n = jt * 16 + l15;
            bfr[jt] = *(const short8*)&Bs[n * 32 + ((quad ^ (n & 3)) << 3)];
        }
#pragma unroll
        for (int i = 0; i < 2; i++)
#pragma unroll
            for (int jt = 0; jt < 4; jt++)
                acc[i][jt] = __builtin_amdgcn_mfma_f32_16x16x32_bf16(
                    af[i], bfr[jt], acc[i][jt], 0, 0, 0);
    }
    // ---- epilogue
#pragma unroll
    for (int i = 0; i < 2; i++) {
        int rbase = rB + w * 32 + i * 16 + quad * 4;
#pragma unroll
        for (int jt = 0; jt < 4; jt++) {
            int col = nB + jt * 16 + l15;
            float bcol = bias[col];
#pragma unroll
            for (int reg = 0; reg < 4; reg++) {
                int r = rbase + reg;
                if (r < M) {
                    float v = acc[i][jt][reg] + bcol;
                    if (EPI == 1) v = 0.5f * v * (1.f + erff(v * 0.70710678118654752f));
                    if (EPI == 2) v += res[(size_t)r * N + col];
                    C[(size_t)r * N + col] = v;
                }
            }
        }
    }
}

// ---------------------------------------------------------------------------
// Fused attention (unchanged from R2): per-camera blocks, conflict-free LDS,
// unnormalized accumulate + Z partials (normalization fused into ln_pre).
// ---------------------------------------------------------------------------
#define TQ 32
#define CHUNK 64

__global__ __launch_bounds__(256) void attn_kernel(
    const float* __restrict__ qf, const float* __restrict__ kf,
    const float* __restrict__ vf, float* __restrict__ attn_out,
    float* __restrict__ Zp)
{
    const int qt  = blockIdx.x;
    const int bm  = blockIdx.y;
    const int cam = blockIdx.z;
    const int b = bm >> 3, m = bm & 7;
    const int q0 = qt * TQ;
    const int tid = threadIdx.x;

    __shared__ __align__(16) float qs[TQ][DH + 1];
    __shared__ __align__(16) float kst[DH][CHUNK + 4];
    __shared__ __align__(16) float vs[CHUNK][DH];
    __shared__ __align__(16) float ps[TQ][CHUNK + 4];

    for (int idx = tid; idx < TQ * DH; idx += 256) {
        int q = idx >> 5, d = idx & 31;
        float v = 0.f;
        if (q0 + q < HW)
            v = qf[(((size_t)(b * 6 + cam) * HW) + q0 + q) * DIM + m * DH + d];
        qs[q][d] = v;
    }

    const float* kbase = kf + (size_t)(b * 6 + cam) * KP * DIM + m * DH;
    const float* vbase = vf + (size_t)(b * 6 + cam) * KP * DIM + m * DH;

    float acc[4] = {0.f, 0.f, 0.f, 0.f};
    float zacc = 0.f;
    const float scale = 0.17677669529663687f;

    const int qp = tid >> 4, kg = tid & 15;
    const int qa = qp * 2,  j0 = kg * 4;
    const int qq = tid >> 3;
    const int dh0 = (tid & 7) << 2;

    for (int c0 = 0; c0 < KP; c0 += CHUNK) {
        const int nk = min(CHUNK, KP - c0);
        __syncthreads();
        for (int l = 0; l < 2; l++) {
            int idx = tid + l * 256;
            int j = idx >> 3, d4 = (idx & 7) << 2;
            float4 kv = {0, 0, 0, 0}, vv = {0, 0, 0, 0};
            if (j < nk) {
                kv = *(const float4*)&kbase[(size_t)(c0 + j) * DIM + d4];
                vv = *(const float4*)&vbase[(size_t)(c0 + j) * DIM + d4];
            }
            kst[d4 + 0][j] = kv.x; kst[d4 + 1][j] = kv.y;
            kst[d4 + 2][j] = kv.z; kst[d4 + 3][j] = kv.w;
            *(float4*)&vs[j][d4] = vv;
        }
        __syncthreads();
        {
            float s0[4] = {0, 0, 0, 0}, s1[4] = {0, 0, 0, 0};
#pragma unroll
            for (int d = 0; d < DH; d++) {
                float a0 = qs[qa][d];
                float a1 = qs[qa + 1][d];
                float4 k4 = *(const float4*)&kst[d][j0];
                s0[0] += a0 * k4.x; s0[1] += a0 * k4.y;
                s0[2] += a0 * k4.z; s0[3] += a0 * k4.w;
                s1[0] += a1 * k4.x; s1[1] += a1 * k4.y;
                s1[2] += a1 * k4.z; s1[3] += a1 * k4.w;
            }
            float4 e0, e1;
            e0.x = (j0 + 0 < nk) ? __expf(scale * s0[0]) : 0.f;
            e0.y = (j0 + 1 < nk) ? __expf(scale * s0[1]) : 0.f;
            e0.z = (j0 + 2 < nk) ? __expf(scale * s0[2]) : 0.f;
            e0.w = (j0 + 3 < nk) ? __expf(scale * s0[3]) : 0.f;
            e1.x = (j0 + 0 < nk) ? __expf(scale * s1[0]) : 0.f;
            e1.y = (j0 + 1 < nk) ? __expf(scale * s1[1]) : 0.f;
            e1.z = (j0 + 2 < nk) ? __expf(scale * s1[2]) : 0.f;
            e1.w = (j0 + 3 < nk) ? __expf(scale * s1[3]) : 0.f;
            *(float4*)&ps[qa][j0]     = e0;
            *(float4*)&ps[qa + 1][j0] = e1;
        }
        __syncthreads();
#pragma unroll 8
        for (int j = 0; j < CHUNK; j++) {
            float p = ps[qq][j];
            float4 v4 = *(const float4*)&vs[j][dh0];
            zacc += p;
            acc[0] += p * v4.x; acc[1] += p * v4.y;
            acc[2] += p * v4.z; acc[3] += p * v4.w;
        }
    }
    if (q0 + qq < HW) {
        size_t rowbase = ((size_t)b * HW + q0 + qq) * NDIM + cam * DIM + m * DH + dh0;
        float4 o; o.x = acc[0]; o.y = acc[1]; o.z = acc[2]; o.w = acc[3];
        *(float4*)&attn_out[rowbase] = o;
        if ((tid & 7) == 0)
            Zp[((size_t)(b * 8 + m) * 6 + cam) * HW + q0 + qq] = zacc;
    }
}

// ---------------------------------------------------------------------------
// LayerNorm over 1536 with fused joint-softmax normalization, in place.
// ---------------------------------------------------------------------------
__global__ __launch_bounds__(256) void ln_pre_kernel(
    float* __restrict__ x, const float* __restrict__ Zp,
    const float* __restrict__ g, const float* __restrict__ bt)
{
    const int row = blockIdx.x;
    const int tid = threadIdx.x;
    const int b = row / 2500, q = row % 2500;
    __shared__ float zinv[8];
    if (tid < 8) {
        float z = 0.f;
#pragma unroll
        for (int cam = 0; cam < 6; cam++)
            z += Zp[((size_t)(b * 8 + tid) * 6 + cam) * HW + q];
        zinv[tid] = 1.f / z;
    }
    __syncthreads();
    float* p = x + (size_t)row * NDIM;
    float v[6];
    float s = 0.f, ss = 0.f;
#pragma unroll
    for (int i = 0; i < 6; i++) {
        int c = tid + i * 256;
        v[i] = p[c] * zinv[(c >> 5) & 7];
        s += v[i]; ss += v[i] * v[i];
    }
    __shared__ float rs[4], rss[4];
    int lane = tid & 63, wid = tid >> 6;
#pragma unroll
    for (int o = 32; o > 0; o >>= 1) { s += __shfl_down(s, o); ss += __shfl_down(ss, o); }
    if (lane == 0) { rs[wid] = s; rss[wid] = ss; }
    __syncthreads();
    s = rs[0] + rs[1] + rs[2] + rs[3];
    ss = rss[0] + rss[1] + rss[2] + rss[3];
    float mu = s * (1.f / NDIM);
    float var = ss * (1.f / NDIM) - mu * mu;
    float inv = rsqrtf(var + 1e-5f);
#pragma unroll
    for (int i = 0; i < 6; i++) {
        int c = tid + i * 256;
        p[c] = (v[i] - mu) * inv * g[c] + bt[c];
    }
}

// ---------------------------------------------------------------------------
// Final: out[b,c,hw] = x[row,c] + LN256(y2[row]) * g + b.
// ---------------------------------------------------------------------------
__global__ __launch_bounds__(256) void final_kernel(
    const float* __restrict__ x, const float* __restrict__ y2,
    const float* __restrict__ g, const float* __restrict__ bt,
    float* __restrict__ out)
{
    const int row = blockIdx.x;
    const int tid = threadIdx.x;
    float v = y2[(size_t)row * DIM + tid];
    float s = v, ss = v * v;
    __shared__ float rs[4], rss[4];
    int lane = tid & 63, wid = tid >> 6;
#pragma unroll
    for (int o = 32; o > 0; o >>= 1) { s += __shfl_down(s, o); ss += __shfl_down(ss, o); }
    if (lane == 0) { rs[wid] = s; rss[wid] = ss; }
    __syncthreads();
    s = rs[0] + rs[1] + rs[2] + rs[3];
    ss = rss[0] + rss[1] + rss[2] + rss[3];
    float mu = s * (1.f / DIM);
    float var = ss * (1.f / DIM) - mu * mu;
    float inv = rsqrtf(var + 1e-5f);
    float r = x[(size_t)row * DIM + tid] + (v - mu) * inv * g[tid] + bt[tid];
    int b = row / 2500, hw = row % 2500;
    out[(size_t)b * 640000 + (size_t)tid * 2500 + hw] = r;
}

// ---------------------------------------------------------------------------
extern "C" void kernel_launch(void* const* d_in, const int* in_sizes, int n_in,
                              void* d_out, int out_size, void* d_ws, size_t ws_size,
                              hipStream_t stream)
{
    const float* q     = (const float*)d_in[0];
    const float* k     = (const float*)d_in[1];
    const float* v     = (const float*)d_in[2];
    const float* Wq    = (const float*)d_in[3];
    const float* bq    = (const float*)d_in[4];
    const float* Wk    = (const float*)d_in[5];
    const float* bk    = (const float*)d_in[6];
    const float* Wv    = (const float*)d_in[7];
    const float* bv    = (const float*)d_in[8];
    const float* Wproj = (const float*)d_in[9];
    const float* bproj = (const float*)d_in[10];
    const float* Waddq = (const float*)d_in[11];
    const float* baddq = (const float*)d_in[12];
    const float* W1    = (const float*)d_in[13];
    const float* b1    = (const float*)d_in[14];
    const float* W2    = (const float*)d_in[15];
    const float* b2    = (const float*)d_in[16];
    const float* g_pre = (const float*)d_in[17];
    const float* b_pre = (const float*)d_in[18];
    const float* g_nrm = (const float*)d_in[19];
    const float* b_nrm = (const float*)d_in[20];
    float* out = (float*)d_out;

    // workspace layout (floats) — same footprint as R2
    float* ws = (float*)d_ws;
    float* qf       = ws;                    // 7,680,000
    float* kf       = qf + 7680000;          // 1,920,000
    float* vfb      = kf + 1920000;          // 1,920,000
    float* add_q    = vfb + 1920000;         // 1,280,000
    float* attn_out = add_q + 1280000;       // 7,680,000
    float* x        = attn_out + 7680000;    // 1,280,000
    float* h1       = x + 1280000;           // 2,560,000
    float* y2       = h1 + 2560000;          // 1,280,000
    // Zp (240,000 floats) aliases h1[0:240000]: attn writes, ln_pre reads,
    // both before the W1 GEMM writes h1.
    float* Zp       = h1;
    // Early bf16 weights alias h1[240000:534912] (dead once add_q GEMM done,
    // overwritten later by W1 GEMM output — safe in stream order).
    short* eW = (short*)(h1 + 240000);
    short* Wq_t    = eW;                 // 65,536
    short* Wk_t    = eW + 65536;         // 65,536
    short* Wv_t    = eW + 131072;        // 65,536
    short* Waddq_t = eW + 196608;        // 393,216
    // Late bf16 weights alias qf[0:327680] (qf dead after attn_kernel);
    // converted after attn, consumed by proj/W1/W2 GEMMs.
    short* lW = (short*)qf;
    short* Wproj_t = lW;                 // 393,216
    short* W1_t    = lW + 393216;        // 131,072
    short* W2_t    = lW + 524288;        // 131,072

    dim3 blk(256);

    // ---- convert early weights (Wq, Wk, Wv, Waddq)
    {
        WtArgs a;
        a.j[0] = {Wq,    Wq_t,    256,  256};
        a.j[1] = {Wk,    Wk_t,    256,  256};
        a.j[2] = {Wv,    Wv_t,    256,  256};
        a.j[3] = {Waddq, Waddq_t, 1536, 256};
        wtconv<<<dim3(8, 48, 4), blk, 0, stream>>>(a);
    }
    // ---- input-side GEMMs (bf16 MFMA)
    mgemm<1, 0><<<dim3(4, 235), blk, 0, stream>>>(q, Wq_t, bq, nullptr, qf, 30000, 256, 256);
    mgemm<3, 0><<<dim3(4, 59),  blk, 0, stream>>>(k, Wk_t, bk, nullptr, kf, 7500, 256, 256);
    mgemm<3, 0><<<dim3(4, 59),  blk, 0, stream>>>(v, Wv_t, bv, nullptr, vfb, 7500, 256, 256);
    mgemm<2, 0><<<dim3(4, 40),  blk, 0, stream>>>(q, Waddq_t, baddq, nullptr, add_q, 5000, 256, 1536);
    // ---- attention
    attn_kernel<<<dim3(79, 16, 6), blk, 0, stream>>>(qf, kf, vfb, attn_out, Zp);
    // ---- convert late weights (Wproj, W1, W2) into dead qf region
    {
        WtArgs a;
        a.j[0] = {Wproj, Wproj_t, 1536, 256};
        a.j[1] = {W1,    W1_t,    256,  512};
        a.j[2] = {W2,    W2_t,    512,  256};
        a.j[3] = {W2,    W2_t,    512,  256};   // dup, grid.z=3 never reaches
        wtconv<<<dim3(16, 48, 3), blk, 0, stream>>>(a);
    }
    // ---- tail: LN + proj + FFN + final
    ln_pre_kernel<<<dim3(5000), blk, 0, stream>>>(attn_out, Zp, g_pre, b_pre);
    mgemm<0, 2><<<dim3(4, 40), blk, 0, stream>>>(attn_out, Wproj_t, bproj, add_q, x, 5000, 256, 1536);
    mgemm<0, 1><<<dim3(8, 40), blk, 0, stream>>>(x, W1_t, b1, nullptr, h1, 5000, 512, 256);
    mgemm<0, 0><<<dim3(4, 40), blk, 0, stream>>>(h1, W2_t, b2, nullptr, y2, 5000, 256, 512);
    final_kernel<<<dim3(5000), blk, 0, stream>>>(x, y2, g_nrm, b_nrm, out);
}

// Round 4
// 459.146 us; speedup vs baseline: 7.1414x; 1.6868x over previous
//
#include <hip/hip_runtime.h>
#include <math.h>

// Problem constants
#define BATCH 2
#define NCAM 6
#define DIM 256
#define HEADS 8
#define DH 32
#define HW 2500          // 50*50
#define KP 625           // 25*25 pooled keys per cam
#define NDIM (NCAM*DIM)  // 1536

typedef __attribute__((ext_vector_type(8))) short short8;
typedef __attribute__((ext_vector_type(4))) float f32x4;

__device__ __forceinline__ short f2bf(float f) {
    union { float f; unsigned u; } v; v.f = f;
    unsigned r = v.u + 0x7fffu + ((v.u >> 16) & 1u);   // round-to-nearest-even
    return (short)(r >> 16);
}
__device__ __forceinline__ float bf2f(short h) {
    union { unsigned u; float f; } v; v.u = ((unsigned)(unsigned short)h) << 16;
    return v.f;
}

// ---------------------------------------------------------------------------
// Weight transpose+convert: Wt[n*K+k] = bf16(W[k*N+n]).  32x32 LDS tiles.
// ---------------------------------------------------------------------------
struct WtJob { const float* src; short* dst; int K, N; };
struct WtArgs { WtJob j[4]; };

__global__ __launch_bounds__(256) void wtconv(WtArgs args) {
    WtJob jb = args.j[blockIdx.z];
    int nB = blockIdx.x * 32, kB = blockIdx.y * 32;
    if (nB >= jb.N || kB >= jb.K) return;
    __shared__ float t[32][33];
    int tx = threadIdx.x & 31, ty = threadIdx.x >> 5;
#pragma unroll
    for (int i = 0; i < 32; i += 8)
        t[ty + i][tx] = jb.src[(size_t)(kB + ty + i) * jb.N + nB + tx];
    __syncthreads();
#pragma unroll
    for (int i = 0; i < 32; i += 8)
        jb.dst[(size_t)(nB + ty + i) * jb.K + kB + tx] = f2bf(t[tx][ty + i]);
}

// ---------------------------------------------------------------------------
// bf16 MFMA GEMM (as R3) + OBF: 0 = fp32 output, 1 = bf16 output.
// ---------------------------------------------------------------------------
template<int MODE, int EPI, int OBF>
__global__ __launch_bounds__(256) void mgemm(
    const float* __restrict__ A, const short* __restrict__ Bt,
    const float* __restrict__ bias, const float* __restrict__ res,
    float* __restrict__ C, int M, int N, int K)
{
    __shared__ short As[128 * 32];
    __shared__ short Bs[64 * 32];

    const int tid  = threadIdx.x;
    const int nB   = blockIdx.x * 64;
    const int rB   = blockIdx.y * 128;
    const int w    = tid >> 6;
    const int lane = tid & 63;
    const int l15  = lane & 15;
    const int quad = lane >> 4;

    f32x4 acc[2][4];
#pragma unroll
    for (int i = 0; i < 2; i++)
#pragma unroll
        for (int jt = 0; jt < 4; jt++) acc[i][jt] = (f32x4){0.f, 0.f, 0.f, 0.f};

    for (int kB = 0; kB < K; kB += 32) {
        __syncthreads();
        if (MODE == 0) {
            int r = tid >> 1, k0 = (tid & 1) * 16;
            int rg = rB + r;
            short tmp[16];
            if (rg < M) {
                const float* p = &A[(size_t)rg * K + kB + k0];
#pragma unroll
                for (int j = 0; j < 16; j += 4) {
                    float4 f = *(const float4*)&p[j];
                    tmp[j] = f2bf(f.x); tmp[j + 1] = f2bf(f.y);
                    tmp[j + 2] = f2bf(f.z); tmp[j + 3] = f2bf(f.w);
                }
            } else {
#pragma unroll
                for (int j = 0; j < 16; j++) tmp[j] = 0;
            }
            int g0 = k0 >> 3;
            *(short8*)&As[r * 32 + ((g0 ^ (r & 3)) << 3)]       = *(short8*)&tmp[0];
            *(short8*)&As[r * 32 + (((g0 + 1) ^ (r & 3)) << 3)] = *(short8*)&tmp[8];
        } else {
            int r = tid & 127, k0 = (tid >> 7) * 16;
            int rg = rB + r;
            short tmp[16];
            if (rg < M) {
                if (MODE == 1) {
                    int slab = rg / 2500, hw = rg % 2500;
                    const float* p = A + (size_t)slab * 640000 + hw;
#pragma unroll
                    for (int j = 0; j < 16; j++)
                        tmp[j] = f2bf(p[(size_t)(kB + k0 + j) * 2500]);
                } else if (MODE == 2) {
                    int bb = rg / 2500, hw = rg % 2500;
#pragma unroll
                    for (int j = 0; j < 16; j++) {
                        int kk = kB + k0 + j;
                        int cam = kk >> 8, c = kk & 255;
                        tmp[j] = f2bf(A[(size_t)bb * 3840000 + cam * 640000 + c * 2500 + hw]);
                    }
                } else { // POOL
                    int slab = rg / 625, kp = rg % 625;
                    int i2 = (kp / 25) * 2, j2 = (kp % 25) * 2;
                    const float* p = A + (size_t)slab * 640000 + i2 * 50 + j2;
#pragma unroll
                    for (int j = 0; j < 16; j++) {
                        const float* p0 = p + (size_t)(kB + k0 + j) * 2500;
                        tmp[j] = f2bf(0.25f * (p0[0] + p0[1] + p0[50] + p0[51]));
                    }
                }
            } else {
#pragma unroll
                for (int j = 0; j < 16; j++) tmp[j] = 0;
            }
            int g0 = k0 >> 3;
            *(short8*)&As[r * 32 + ((g0 ^ (r & 3)) << 3)]       = *(short8*)&tmp[0];
            *(short8*)&As[r * 32 + (((g0 + 1) ^ (r & 3)) << 3)] = *(short8*)&tmp[8];
        }
        {
            int n = tid >> 2, gk = tid & 3;
            short8 bv = *(const short8*)&Bt[(size_t)(nB + n) * K + kB + gk * 8];
            *(short8*)&Bs[n * 32 + ((gk ^ (n & 3)) << 3)] = bv;
        }
        __syncthreads();
        short8 af[2], bfr[4];
#pragma unroll
        for (int i = 0; i < 2; i++) {
            int m = w * 32 + i * 16 + l15;
            af[i] = *(const short8*)&As[m * 32 + ((quad ^ (m & 3)) << 3)];
        }
#pragma unroll
        for (int jt = 0; jt < 4; jt++) {
            int n = jt * 16 + l15;
            bfr[jt] = *(const short8*)&Bs[n * 32 + ((quad ^ (n & 3)) << 3)];
        }
#pragma unroll
        for (int i = 0; i < 2; i++)
#pragma unroll
            for (int jt = 0; jt < 4; jt++)
                acc[i][jt] = __builtin_amdgcn_mfma_f32_16x16x32_bf16(
                    af[i], bfr[jt], acc[i][jt], 0, 0, 0);
    }
#pragma unroll
    for (int i = 0; i < 2; i++) {
        int rbase = rB + w * 32 + i * 16 + quad * 4;
#pragma unroll
        for (int jt = 0; jt < 4; jt++) {
            int col = nB + jt * 16 + l15;
            float bcol = bias[col];
#pragma unroll
            for (int reg = 0; reg < 4; reg++) {
                int r = rbase + reg;
                if (r < M) {
                    float v = acc[i][jt][reg] + bcol;
                    if (EPI == 1) v = 0.5f * v * (1.f + erff(v * 0.70710678118654752f));
                    if (EPI == 2) v += res[(size_t)r * N + col];
                    if (OBF) ((short*)C)[(size_t)r * N + col] = f2bf(v);
                    else     C[(size_t)r * N + col] = v;
                }
            }
        }
    }
}

// ---------------------------------------------------------------------------
// MFMA attention: block = 64 queries x (b,m,cam). grid (40, 16, 6), block 256.
// Wave w owns queries q0+w*16..+15. Per 64-key chunk:
//   stage Ks[key][dh] (B-frag-ready) + Vt[dh][key] (XOR-swizzled key groups),
//   S = Q@K^T via 4 MFMAs, exp+mask in C-layout regs, P -> wave-private LDS
//   (A-layout; same-wave write->read, no barrier), PV via 4 MFMAs.
// Unnormalized output + Z partials; normalization fused into ln_pre.
// ---------------------------------------------------------------------------
#define TQA 64
#define CH 64
#define VSTR 72    // u16 stride for Vt/Pl rows: 144 B = 9 x 16B units, odd group spread

__global__ __launch_bounds__(256) void attn_mfma(
    const short* __restrict__ qf, const short* __restrict__ kf,
    const short* __restrict__ vf, float* __restrict__ attn_out,
    float* __restrict__ Zp)
{
    const int qt  = blockIdx.x;
    const int bm  = blockIdx.y;
    const int cam = blockIdx.z;
    const int b = bm >> 3, m = bm & 7;
    const int q0 = qt * TQA;
    const int tid = threadIdx.x;
    const int w = tid >> 6, lane = tid & 63;
    const int l15 = lane & 15, quad = lane >> 4;

    __shared__ __align__(16) short Ks[CH][DH];      // 4 KB
    __shared__ __align__(16) short Vt[DH][VSTR];    // 4.6 KB
    __shared__ __align__(16) short Pl[TQA][VSTR];   // 9.2 KB

    const size_t slab = (size_t)(b * 6 + cam);

    // Q A-frag for this wave (reused every chunk); clamp OOB queries to a
    // valid row so no garbage (exp overflow) ever enters the pipeline.
    int qrow = q0 + w * 16 + l15;
    int qcl  = qrow < HW ? qrow : HW - 1;
    const short8 aq = *(const short8*)&qf[(slab * HW + qcl) * DIM + m * DH + quad * 8];

    const short* kb = kf + slab * KP * DIM + m * DH;
    const short* vb = vf + slab * KP * DIM + m * DH;

    f32x4 oacc[2];
    oacc[0] = (f32x4){0.f, 0.f, 0.f, 0.f};
    oacc[1] = (f32x4){0.f, 0.f, 0.f, 0.f};
    float zp[4] = {0.f, 0.f, 0.f, 0.f};
    const float scale = 0.17677669529663687f;   // 1/sqrt(32)

    // staging mapping: thread -> (local key kl = tid>>2, dh group d8 = (tid&3)*8)
    const int kl = tid >> 2, d8 = (tid & 3) * 8;
    const int vcol = (((kl >> 3) ^ (d8 >> 3)) << 3) | (kl & 7);  // swizzled V col

    for (int c0 = 0; c0 < KP; c0 += CH) {
        __syncthreads();   // prev chunk's MFMA reads of Ks/Vt done
        {
            int key = c0 + kl;
            short8 kv8 = {0, 0, 0, 0, 0, 0, 0, 0};
            short8 vv8 = {0, 0, 0, 0, 0, 0, 0, 0};
            if (key < KP) {
                kv8 = *(const short8*)&kb[(size_t)key * DIM + d8];
                vv8 = *(const short8*)&vb[(size_t)key * DIM + d8];
            }
            *(short8*)&Ks[kl][d8] = kv8;
#pragma unroll
            for (int t = 0; t < 8; t++) Vt[d8 + t][vcol] = vv8[t];
        }
        __syncthreads();
        // ---- S phase: 4 key-tiles, K=32 covers full dh in one MFMA each
        f32x4 sfrag[4];
#pragma unroll
        for (int jt = 0; jt < 4; jt++) {
            short8 bk8 = *(const short8*)&Ks[jt * 16 + l15][quad * 8];
            sfrag[jt] = __builtin_amdgcn_mfma_f32_16x16x32_bf16(
                aq, bk8, (f32x4){0.f, 0.f, 0.f, 0.f}, 0, 0, 0);
        }
        // ---- exp + key mask, write P (bf16) to wave-private LDS rows,
        //      accumulate Z from the bf16-rounded P (consistent with PV)
#pragma unroll
        for (int jt = 0; jt < 4; jt++) {
            bool valid = (c0 + jt * 16 + l15) < KP;
#pragma unroll
            for (int reg = 0; reg < 4; reg++) {
                float p = valid ? __expf(scale * sfrag[jt][reg]) : 0.f;
                short ph = f2bf(p);
                zp[reg] += bf2f(ph);
                Pl[w * 16 + quad * 4 + reg][jt * 16 + l15] = ph;
            }
        }
        // ---- PV phase: 2 k-steps (32 keys) x 2 dh-tiles
#pragma unroll
        for (int ks = 0; ks < 2; ks++) {
            short8 ap = *(const short8*)&Pl[w * 16 + l15][ks * 32 + quad * 8];
#pragma unroll
            for (int nt = 0; nt < 2; nt++) {
                int dhn = nt * 16 + l15;
                int pgrp = ((ks * 4 + quad) ^ (dhn >> 3));
                short8 bv8 = *(const short8*)&Vt[dhn][pgrp << 3];
                oacc[nt] = __builtin_amdgcn_mfma_f32_16x16x32_bf16(
                    ap, bv8, oacc[nt], 0, 0, 0);
            }
        }
    }
    // ---- reduce Z across the 16 lanes of each quad (rows q=quad*4+reg)
#pragma unroll
    for (int off = 1; off < 16; off <<= 1)
#pragma unroll
        for (int reg = 0; reg < 4; reg++)
            zp[reg] += __shfl_xor(zp[reg], off, 64);
    // ---- epilogue: unnormalized out (C-layout) + Z partial
#pragma unroll
    for (int reg = 0; reg < 4; reg++) {
        int q = q0 + w * 16 + quad * 4 + reg;
        if (q < HW) {
            size_t rowb = ((size_t)b * HW + q) * NDIM + cam * DIM + m * DH;
            attn_out[rowb + l15]      = oacc[0][reg];
            attn_out[rowb + 16 + l15] = oacc[1][reg];
            if (l15 == 0)
                Zp[((size_t)bm * 6 + cam) * HW + q] = zp[reg];
        }
    }
}

// ---------------------------------------------------------------------------
// LayerNorm over 1536 with fused joint-softmax normalization, in place.
// ---------------------------------------------------------------------------
__global__ __launch_bounds__(256) void ln_pre_kernel(
    float* __restrict__ x, const float* __restrict__ Zp,
    const float* __restrict__ g, const float* __restrict__ bt)
{
    const int row = blockIdx.x;
    const int tid = threadIdx.x;
    const int b = row / 2500, q = row % 2500;
    __shared__ float zinv[8];
    if (tid < 8) {
        float z = 0.f;
#pragma unroll
        for (int cam = 0; cam < 6; cam++)
            z += Zp[((size_t)(b * 8 + tid) * 6 + cam) * HW + q];
        zinv[tid] = 1.f / z;
    }
    __syncthreads();
    float* p = x + (size_t)row * NDIM;
    float v[6];
    float s = 0.f, ss = 0.f;
#pragma unroll
    for (int i = 0; i < 6; i++) {
        int c = tid + i * 256;
        v[i] = p[c] * zinv[(c >> 5) & 7];
        s += v[i]; ss += v[i] * v[i];
    }
    __shared__ float rs[4], rss[4];
    int lane = tid & 63, wid = tid >> 6;
#pragma unroll
    for (int o = 32; o > 0; o >>= 1) { s += __shfl_down(s, o); ss += __shfl_down(ss, o); }
    if (lane == 0) { rs[wid] = s; rss[wid] = ss; }
    __syncthreads();
    s = rs[0] + rs[1] + rs[2] + rs[3];
    ss = rss[0] + rss[1] + rss[2] + rss[3];
    float mu = s * (1.f / NDIM);
    float var = ss * (1.f / NDIM) - mu * mu;
    float inv = rsqrtf(var + 1e-5f);
#pragma unroll
    for (int i = 0; i < 6; i++) {
        int c = tid + i * 256;
        p[c] = (v[i] - mu) * inv * g[c] + bt[c];
    }
}

// ---------------------------------------------------------------------------
// Final: out[b,c,hw] = x[row,c] + LN256(y2[row]) * g + b.
// ---------------------------------------------------------------------------
__global__ __launch_bounds__(256) void final_kernel(
    const float* __restrict__ x, const float* __restrict__ y2,
    const float* __restrict__ g, const float* __restrict__ bt,
    float* __restrict__ out)
{
    const int row = blockIdx.x;
    const int tid = threadIdx.x;
    float v = y2[(size_t)row * DIM + tid];
    float s = v, ss = v * v;
    __shared__ float rs[4], rss[4];
    int lane = tid & 63, wid = tid >> 6;
#pragma unroll
    for (int o = 32; o > 0; o >>= 1) { s += __shfl_down(s, o); ss += __shfl_down(ss, o); }
    if (lane == 0) { rs[wid] = s; rss[wid] = ss; }
    __syncthreads();
    s = rs[0] + rs[1] + rs[2] + rs[3];
    ss = rss[0] + rss[1] + rss[2] + rss[3];
    float mu = s * (1.f / DIM);
    float var = ss * (1.f / DIM) - mu * mu;
    float inv = rsqrtf(var + 1e-5f);
    float r = x[(size_t)row * DIM + tid] + (v - mu) * inv * g[tid] + bt[tid];
    int b = row / 2500, hw = row % 2500;
    out[(size_t)b * 640000 + (size_t)tid * 2500 + hw] = r;
}

// ---------------------------------------------------------------------------
extern "C" void kernel_launch(void* const* d_in, const int* in_sizes, int n_in,
                              void* d_out, int out_size, void* d_ws, size_t ws_size,
                              hipStream_t stream)
{
    const float* q     = (const float*)d_in[0];
    const float* k     = (const float*)d_in[1];
    const float* v     = (const float*)d_in[2];
    const float* Wq    = (const float*)d_in[3];
    const float* bq    = (const float*)d_in[4];
    const float* Wk    = (const float*)d_in[5];
    const float* bk    = (const float*)d_in[6];
    const float* Wv    = (const float*)d_in[7];
    const float* bv    = (const float*)d_in[8];
    const float* Wproj = (const float*)d_in[9];
    const float* bproj = (const float*)d_in[10];
    const float* Waddq = (const float*)d_in[11];
    const float* baddq = (const float*)d_in[12];
    const float* W1    = (const float*)d_in[13];
    const float* b1    = (const float*)d_in[14];
    const float* W2    = (const float*)d_in[15];
    const float* b2    = (const float*)d_in[16];
    const float* g_pre = (const float*)d_in[17];
    const float* b_pre = (const float*)d_in[18];
    const float* g_nrm = (const float*)d_in[19];
    const float* b_nrm = (const float*)d_in[20];
    float* out = (float*)d_out;

    // workspace layout (float-unit offsets; qf/kf/vfb now hold bf16 in the
    // same regions — half-used, offsets unchanged from R3)
    float* ws = (float*)d_ws;
    float* qf       = ws;                    // 7,680,000
    float* kf       = qf + 7680000;          // 1,920,000
    float* vfb      = kf + 1920000;          // 1,920,000
    float* add_q    = vfb + 1920000;         // 1,280,000
    float* attn_out = add_q + 1280000;       // 7,680,000
    float* x        = attn_out + 7680000;    // 1,280,000
    float* h1       = x + 1280000;           // 2,560,000
    float* y2       = h1 + 2560000;          // 1,280,000
    float* Zp       = h1;                    // alias: attn writes, ln_pre reads,
                                             // both before W1 GEMM writes h1
    short* eW = (short*)(h1 + 240000);
    short* Wq_t    = eW;                 // 65,536
    short* Wk_t    = eW + 65536;
    short* Wv_t    = eW + 131072;
    short* Waddq_t = eW + 196608;        // 393,216
    short* lW = (short*)qf;              // qf dead after attn
    short* Wproj_t = lW;                 // 393,216
    short* W1_t    = lW + 393216;        // 131,072
    short* W2_t    = lW + 524288;        // 131,072

    dim3 blk(256);

    {
        WtArgs a;
        a.j[0] = {Wq,    Wq_t,    256,  256};
        a.j[1] = {Wk,    Wk_t,    256,  256};
        a.j[2] = {Wv,    Wv_t,    256,  256};
        a.j[3] = {Waddq, Waddq_t, 1536, 256};
        wtconv<<<dim3(8, 48, 4), blk, 0, stream>>>(a);
    }
    // input-side GEMMs -> bf16 outputs (consumed by attn_mfma)
    mgemm<1, 0, 1><<<dim3(4, 235), blk, 0, stream>>>(q, Wq_t, bq, nullptr, qf, 30000, 256, 256);
    mgemm<3, 0, 1><<<dim3(4, 59),  blk, 0, stream>>>(k, Wk_t, bk, nullptr, kf, 7500, 256, 256);
    mgemm<3, 0, 1><<<dim3(4, 59),  blk, 0, stream>>>(v, Wv_t, bv, nullptr, vfb, 7500, 256, 256);
    mgemm<2, 0, 0><<<dim3(4, 40),  blk, 0, stream>>>(q, Waddq_t, baddq, nullptr, add_q, 5000, 256, 1536);
    // MFMA attention
    attn_mfma<<<dim3(40, 16, 6), blk, 0, stream>>>(
        (const short*)qf, (const short*)kf, (const short*)vfb, attn_out, Zp);
    // late weights into dead qf region
    {
        WtArgs a;
        a.j[0] = {Wproj, Wproj_t, 1536, 256};
        a.j[1] = {W1,    W1_t,    256,  512};
        a.j[2] = {W2,    W2_t,    512,  256};
        a.j[3] = {W2,    W2_t,    512,  256};   // dup, grid.z=3 never reaches
        wtconv<<<dim3(16, 48, 3), blk, 0, stream>>>(a);
    }
    ln_pre_kernel<<<dim3(5000), blk, 0, stream>>>(attn_out, Zp, g_pre, b_pre);
    mgemm<0, 2, 0><<<dim3(4, 40), blk, 0, stream>>>(attn_out, Wproj_t, bproj, add_q, x, 5000, 256, 1536);
    mgemm<0, 1, 0><<<dim3(8, 40), blk, 0, stream>>>(x, W1_t, b1, nullptr, h1, 5000, 512, 256);
    mgemm<0, 0, 0><<<dim3(4, 40), blk, 0, stream>>>(h1, W2_t, b2, nullptr, y2, 5000, 256, 512);
    final_kernel<<<dim3(5000), blk, 0, stream>>>(x, y2, g_nrm, b_nrm, out);
}

// Round 6
// 381.383 us; speedup vs baseline: 8.5975x; 1.2039x over previous
//
#include <hip/hip_runtime.h>
#include <math.h>

// Problem constants
#define BATCH 2
#define NCAM 6
#define DIM 256
#define HEADS 8
#define DH 32
#define HW 2500          // 50*50
#define KP 625           // 25*25 pooled keys per cam
#define NDIM (NCAM*DIM)  // 1536

typedef __attribute__((ext_vector_type(8))) short short8;
typedef __attribute__((ext_vector_type(4))) float f32x4;

__device__ __forceinline__ short f2bf(float f) {
    union { float f; unsigned u; } v; v.f = f;
    unsigned r = v.u + 0x7fffu + ((v.u >> 16) & 1u);   // round-to-nearest-even
    return (short)(r >> 16);
}
__device__ __forceinline__ float bf2f(short h) {
    union { unsigned u; float f; } v; v.u = ((unsigned)(unsigned short)h) << 16;
    return v.f;
}

// ---------------------------------------------------------------------------
// Weight transpose+convert: Wt[n*K+k] = bf16(W[k*N+n]).  32x32 LDS tiles.
// ---------------------------------------------------------------------------
struct WtJob { const float* src; short* dst; int K, N; };
struct WtArgs { WtJob j[4]; };

__global__ __launch_bounds__(256) void wtconv(WtArgs args) {
    WtJob jb = args.j[blockIdx.z];
    int nB = blockIdx.x * 32, kB = blockIdx.y * 32;
    if (nB >= jb.N || kB >= jb.K) return;
    __shared__ float t[32][33];
    int tx = threadIdx.x & 31, ty = threadIdx.x >> 5;
#pragma unroll
    for (int i = 0; i < 32; i += 8)
        t[ty + i][tx] = jb.src[(size_t)(kB + ty + i) * jb.N + nB + tx];
    __syncthreads();
#pragma unroll
    for (int i = 0; i < 32; i += 8)
        jb.dst[(size_t)(nB + ty + i) * jb.K + kB + tx] = f2bf(t[tx][ty + i]);
}

// ---------------------------------------------------------------------------
// Prep: one-time bf16 conversion of activations.
//   z 0..11 : q slab transpose     qbf[slab][hw][d]   = bf16(q[slab][d][hw])
//   z 12..23: k slab pool+transpose kpbf[slab][kp][d] = bf16(mean2x2 k)
//   z 24..35: v slab pool+transpose
// grid (79, 8, 36), block 256. Pool jobs exit for xB >= 20.
// ---------------------------------------------------------------------------
__global__ __launch_bounds__(256) void prep(
    const float* __restrict__ q, const float* __restrict__ k,
    const float* __restrict__ v, short* __restrict__ qbf,
    short* __restrict__ kpbf, short* __restrict__ vpbf)
{
    __shared__ float t[32][33];
    const int z = blockIdx.z;
    const int tx = threadIdx.x & 31, ty = threadIdx.x >> 5;   // ty 0..7
    const int dB = blockIdx.y * 32;
    if (z < 12) {
        const int slab = z;
        const int hwB = blockIdx.x * 32;
        const float* src = q + (size_t)slab * 640000;
#pragma unroll
        for (int i = 0; i < 32; i += 8) {
            int hw = hwB + tx;
            t[ty + i][tx] = (hw < HW) ? src[(size_t)(dB + ty + i) * HW + hw] : 0.f;
        }
        __syncthreads();
#pragma unroll
        for (int i = 0; i < 32; i += 8) {
            int hw = hwB + ty + i;
            if (hw < HW)
                qbf[((size_t)slab * HW + hw) * DIM + dB + tx] = f2bf(t[tx][ty + i]);
        }
    } else {
        const int kpB = blockIdx.x * 32;
        if (kpB >= KP) return;
        const float* src; short* dst;
        if (z < 24) { src = k + (size_t)(z - 12) * 640000; dst = kpbf + (size_t)(z - 12) * (KP * DIM); }
        else        { src = v + (size_t)(z - 24) * 640000; dst = vpbf + (size_t)(z - 24) * (KP * DIM); }
#pragma unroll
        for (int i = 0; i < 32; i += 8) {
            int kp = kpB + tx;
            float val = 0.f;
            if (kp < KP) {
                int i2 = (kp / 25) * 2, j2 = (kp % 25) * 2;
                const float* p0 = src + (size_t)(dB + ty + i) * HW + i2 * 50 + j2;
                val = 0.25f * (p0[0] + p0[1] + p0[50] + p0[51]);
            }
            t[ty + i][tx] = val;
        }
        __syncthreads();
#pragma unroll
        for (int i = 0; i < 32; i += 8) {
            int kp = kpB + ty + i;
            if (kp < KP)
                dst[(size_t)kp * DIM + dB + tx] = f2bf(t[tx][ty + i]);
        }
    }
}

// ---------------------------------------------------------------------------
// bf16-A MFMA GEMM: C = A[M,K](bf16) @ Bt[N,K]^T + bias (+epilogue).
// BM = 128 (wave: 2x4 tiles) or 64 (wave: 1x4 tiles). BN=64, BK=32.
// ADDQ=1: A row remap for add_q (A=qbf, k=(cam<<8)|c). BM must be 64.
// EPI 0: bias; 1: bias+GELU; 2: bias+res.  WF32: store fp32 C; WBF: bf16 C2.
// ---------------------------------------------------------------------------
template<int BM, int EPI, int WF32, int WBF, int ADDQ>
__global__ __launch_bounds__(256) void mgemm_bf(
    const short* __restrict__ A, const short* __restrict__ Bt,
    const float* __restrict__ bias, const float* __restrict__ res,
    float* __restrict__ C, short* __restrict__ C2, int M, int N, int K)
{
    __shared__ short As[BM * 32];
    __shared__ short Bs[64 * 32];
    constexpr int RT = BM / 64;   // A-frags per wave

    const int tid  = threadIdx.x;
    const int nB   = blockIdx.x * 64;
    const int rB   = blockIdx.y * BM;
    const int w    = tid >> 6;
    const int lane = tid & 63;
    const int l15  = lane & 15;
    const int quad = lane >> 4;

    f32x4 acc[RT][4];
#pragma unroll
    for (int i = 0; i < RT; i++)
#pragma unroll
        for (int jt = 0; jt < 4; jt++) acc[i][jt] = (f32x4){0.f, 0.f, 0.f, 0.f};

    for (int kB = 0; kB < K; kB += 32) {
        __syncthreads();
        // ---- stage A (bf16 short8 loads)
        if (BM == 128) {
            int r = tid >> 1, k0 = (tid & 1) * 16;
            int rg = rB + r;
            short8 a0 = {0, 0, 0, 0, 0, 0, 0, 0}, a1 = a0;
            if (rg < M) {
                const short* p = &A[(size_t)rg * K + kB + k0];
                a0 = *(const short8*)&p[0];
                a1 = *(const short8*)&p[8];
            }
            int g0 = k0 >> 3;
            *(short8*)&As[r * 32 + ((g0 ^ (r & 3)) << 3)]       = a0;
            *(short8*)&As[r * 32 + (((g0 + 1) ^ (r & 3)) << 3)] = a1;
        } else {
            int r = tid >> 2, gk = tid & 3, k0 = gk * 8;
            int rg = rB + r;
            short8 a0 = {0, 0, 0, 0, 0, 0, 0, 0};
            if (rg < M) {
                if (ADDQ) {
                    int bb = rg / 2500, hw = rg % 2500;
                    int kk = kB + k0;
                    int cam = kk >> 8, c = kk & 255;
                    a0 = *(const short8*)&A[(((size_t)(bb * 6 + cam)) * HW + hw) * DIM + c];
                } else {
                    a0 = *(const short8*)&A[(size_t)rg * K + kB + k0];
                }
            }
            *(short8*)&As[r * 32 + ((gk ^ (r & 3)) << 3)] = a0;
        }
        // ---- stage B
        {
            int n = tid >> 2, gk = tid & 3;
            short8 bv = *(const short8*)&Bt[(size_t)(nB + n) * K + kB + gk * 8];
            *(short8*)&Bs[n * 32 + ((gk ^ (n & 3)) << 3)] = bv;
        }
        __syncthreads();
        // ---- fragments + MFMA
        short8 af[RT], bfr[4];
#pragma unroll
        for (int i = 0; i < RT; i++) {
            int m = w * 16 * RT + i * 16 + l15;
            af[i] = *(const short8*)&As[m * 32 + ((quad ^ (m & 3)) << 3)];
        }
#pragma unroll
        for (int jt = 0; jt < 4; jt++) {
            int n = jt * 16 + l15;
            bfr[jt] = *(const short8*)&Bs[n * 32 + ((quad ^ (n & 3)) << 3)];
        }
#pragma unroll
        for (int i = 0; i < RT; i++)
#pragma unroll
            for (int jt = 0; jt < 4; jt++)
                acc[i][jt] = __builtin_amdgcn_mfma_f32_16x16x32_bf16(
                    af[i], bfr[jt], acc[i][jt], 0, 0, 0);
    }
    // ---- epilogue
#pragma unroll
    for (int i = 0; i < RT; i++) {
        int rbase = rB + w * 16 * RT + i * 16 + quad * 4;
#pragma unroll
        for (int jt = 0; jt < 4; jt++) {
            int col = nB + jt * 16 + l15;
            float bcol = bias[col];
#pragma unroll
            for (int reg = 0; reg < 4; reg++) {
                int r = rbase + reg;
                if (r < M) {
                    float vv = acc[i][jt][reg] + bcol;
                    if (EPI == 1) vv = 0.5f * vv * (1.f + erff(vv * 0.70710678118654752f));
                    if (EPI == 2) vv += res[(size_t)r * N + col];
                    if (WF32) C[(size_t)r * N + col] = vv;
                    if (WBF)  C2[(size_t)r * N + col] = f2bf(vv);
                }
            }
        }
    }
}

// ---------------------------------------------------------------------------
// MFMA attention (unchanged from R4): block = 64 queries x (b,m,cam).
// ---------------------------------------------------------------------------
#define TQA 64
#define CH 64
#define VSTR 72

__global__ __launch_bounds__(256) void attn_mfma(
    const short* __restrict__ qf, const short* __restrict__ kf,
    const short* __restrict__ vf, float* __restrict__ attn_out,
    float* __restrict__ Zp)
{
    const int qt  = blockIdx.x;
    const int bm  = blockIdx.y;
    const int cam = blockIdx.z;
    const int b = bm >> 3, m = bm & 7;
    const int q0 = qt * TQA;
    const int tid = threadIdx.x;
    const int w = tid >> 6, lane = tid & 63;
    const int l15 = lane & 15, quad = lane >> 4;

    __shared__ __align__(16) short Ks[CH][DH];
    __shared__ __align__(16) short Vt[DH][VSTR];
    __shared__ __align__(16) short Pl[TQA][VSTR];

    const size_t slab = (size_t)(b * 6 + cam);

    int qrow = q0 + w * 16 + l15;
    int qcl  = qrow < HW ? qrow : HW - 1;
    const short8 aq = *(const short8*)&qf[(slab * HW + qcl) * DIM + m * DH + quad * 8];

    const short* kb = kf + slab * KP * DIM + m * DH;
    const short* vb = vf + slab * KP * DIM + m * DH;

    f32x4 oacc[2];
    oacc[0] = (f32x4){0.f, 0.f, 0.f, 0.f};
    oacc[1] = (f32x4){0.f, 0.f, 0.f, 0.f};
    float zp[4] = {0.f, 0.f, 0.f, 0.f};
    const float scale = 0.17677669529663687f;

    const int kl = tid >> 2, d8 = (tid & 3) * 8;
    const int vcol = (((kl >> 3) ^ (d8 >> 3)) << 3) | (kl & 7);

    for (int c0 = 0; c0 < KP; c0 += CH) {
        __syncthreads();
        {
            int key = c0 + kl;
            short8 kv8 = {0, 0, 0, 0, 0, 0, 0, 0};
            short8 vv8 = {0, 0, 0, 0, 0, 0, 0, 0};
            if (key < KP) {
                kv8 = *(const short8*)&kb[(size_t)key * DIM + d8];
                vv8 = *(const short8*)&vb[(size_t)key * DIM + d8];
            }
            *(short8*)&Ks[kl][d8] = kv8;
#pragma unroll
            for (int t = 0; t < 8; t++) Vt[d8 + t][vcol] = vv8[t];
        }
        __syncthreads();
        f32x4 sfrag[4];
#pragma unroll
        for (int jt = 0; jt < 4; jt++) {
            short8 bk8 = *(const short8*)&Ks[jt * 16 + l15][quad * 8];
            sfrag[jt] = __builtin_amdgcn_mfma_f32_16x16x32_bf16(
                aq, bk8, (f32x4){0.f, 0.f, 0.f, 0.f}, 0, 0, 0);
        }
#pragma unroll
        for (int jt = 0; jt < 4; jt++) {
            bool valid = (c0 + jt * 16 + l15) < KP;
#pragma unroll
            for (int reg = 0; reg < 4; reg++) {
                float p = valid ? __expf(scale * sfrag[jt][reg]) : 0.f;
                short ph = f2bf(p);
                zp[reg] += bf2f(ph);
                Pl[w * 16 + quad * 4 + reg][jt * 16 + l15] = ph;
            }
        }
#pragma unroll
        for (int ks = 0; ks < 2; ks++) {
            short8 ap = *(const short8*)&Pl[w * 16 + l15][ks * 32 + quad * 8];
#pragma unroll
            for (int nt = 0; nt < 2; nt++) {
                int dhn = nt * 16 + l15;
                int pgrp = ((ks * 4 + quad) ^ (dhn >> 3));
                short8 bv8 = *(const short8*)&Vt[dhn][pgrp << 3];
                oacc[nt] = __builtin_amdgcn_mfma_f32_16x16x32_bf16(
                    ap, bv8, oacc[nt], 0, 0, 0);
            }
        }
    }
#pragma unroll
    for (int off = 1; off < 16; off <<= 1)
#pragma unroll
        for (int reg = 0; reg < 4; reg++)
            zp[reg] += __shfl_xor(zp[reg], off, 64);
#pragma unroll
    for (int reg = 0; reg < 4; reg++) {
        int q = q0 + w * 16 + quad * 4 + reg;
        if (q < HW) {
            size_t rowb = ((size_t)b * HW + q) * NDIM + cam * DIM + m * DH;
            attn_out[rowb + l15]      = oacc[0][reg];
            attn_out[rowb + 16 + l15] = oacc[1][reg];
            if (l15 == 0)
                Zp[((size_t)bm * 6 + cam) * HW + q] = zp[reg];
        }
    }
}

// ---------------------------------------------------------------------------
// LayerNorm over 1536 + fused joint-softmax normalization; writes bf16.
// ---------------------------------------------------------------------------
__global__ __launch_bounds__(256) void ln_pre_kernel(
    const float* __restrict__ xin, short* __restrict__ lnbf,
    const float* __restrict__ Zp,
    const float* __restrict__ g, const float* __restrict__ bt)
{
    const int row = blockIdx.x;
    const int tid = threadIdx.x;
    const int b = row / 2500, q = row % 2500;
    __shared__ float zinv[8];
    if (tid < 8) {
        float z = 0.f;
#pragma unroll
        for (int cam = 0; cam < 6; cam++)
            z += Zp[((size_t)(b * 8 + tid) * 6 + cam) * HW + q];
        zinv[tid] = 1.f / z;
    }
    __syncthreads();
    const float* p = xin + (size_t)row * NDIM;
    float v[6];
    float s = 0.f, ss = 0.f;
#pragma unroll
    for (int i = 0; i < 6; i++) {
        int c = tid + i * 256;
        v[i] = p[c] * zinv[(c >> 5) & 7];
        s += v[i]; ss += v[i] * v[i];
    }
    __shared__ float rs[4], rss[4];
    int lane = tid & 63, wid = tid >> 6;
#pragma unroll
    for (int o = 32; o > 0; o >>= 1) { s += __shfl_down(s, o); ss += __shfl_down(ss, o); }
    if (lane == 0) { rs[wid] = s; rss[wid] = ss; }
    __syncthreads();
    s = rs[0] + rs[1] + rs[2] + rs[3];
    ss = rss[0] + rss[1] + rss[2] + rss[3];
    float mu = s * (1.f / NDIM);
    float var = ss * (1.f / NDIM) - mu * mu;
    float inv = rsqrtf(var + 1e-5f);
#pragma unroll
    for (int i = 0; i < 6; i++) {
        int c = tid + i * 256;
        lnbf[(size_t)row * NDIM + c] = f2bf((v[i] - mu) * inv * g[c] + bt[c]);
    }
}

// ---------------------------------------------------------------------------
// Final: out[b,c,hw] = x[row,c] + LN256(y2[row]) * g + b.
// ---------------------------------------------------------------------------
__global__ __launch_bounds__(256) void final_kernel(
    const float* __restrict__ x, const float* __restrict__ y2,
    const float* __restrict__ g, const float* __restrict__ bt,
    float* __restrict__ out)
{
    const int row = blockIdx.x;
    const int tid = threadIdx.x;
    float v = y2[(size_t)row * DIM + tid];
    float s = v, ss = v * v;
    __shared__ float rs[4], rss[4];
    int lane = tid & 63, wid = tid >> 6;
#pragma unroll
    for (int o = 32; o > 0; o >>= 1) { s += __shfl_down(s, o); ss += __shfl_down(ss, o); }
    if (lane == 0) { rs[wid] = s; rss[wid] = ss; }
    __syncthreads();
    s = rs[0] + rs[1] + rs[2] + rs[3];
    ss = rss[0] + rss[1] + rss[2] + rss[3];
    float mu = s * (1.f / DIM);
    float var = ss * (1.f / DIM) - mu * mu;
    float inv = rsqrtf(var + 1e-5f);
    float r = x[(size_t)row * DIM + tid] + (v - mu) * inv * g[tid] + bt[tid];
    int b = row / 2500, hw = row % 2500;
    out[(size_t)b * 640000 + (size_t)tid * 2500 + hw] = r;
}

// ---------------------------------------------------------------------------
extern "C" void kernel_launch(void* const* d_in, const int* in_sizes, int n_in,
                              void* d_out, int out_size, void* d_ws, size_t ws_size,
                              hipStream_t stream)
{
    const float* q     = (const float*)d_in[0];
    const float* k     = (const float*)d_in[1];
    const float* v     = (const float*)d_in[2];
    const float* Wq    = (const float*)d_in[3];
    const float* bq    = (const float*)d_in[4];
    const float* Wk    = (const float*)d_in[5];
    const float* bk    = (const float*)d_in[6];
    const float* Wv    = (const float*)d_in[7];
    const float* bv    = (const float*)d_in[8];
    const float* Wproj = (const float*)d_in[9];
    const float* bproj = (const float*)d_in[10];
    const float* Waddq = (const float*)d_in[11];
    const float* baddq = (const float*)d_in[12];
    const float* W1    = (const float*)d_in[13];
    const float* b1    = (const float*)d_in[14];
    const float* W2    = (const float*)d_in[15];
    const float* b2    = (const float*)d_in[16];
    const float* g_pre = (const float*)d_in[17];
    const float* b_pre = (const float*)d_in[18];
    const float* g_nrm = (const float*)d_in[19];
    const float* b_nrm = (const float*)d_in[20];
    float* out = (float*)d_out;

    // workspace layout (float-unit offsets)
    // R5 bug: h1bf (13.2M) overlapped xbf [12.8M,13.44M) -> W1 GEMM clobbered
    // its own A while other blocks read it. h1bf now starts at 13.44M.
    float* ws = (float*)d_ws;
    short* qf_a   = (short*)(ws);             // 7.68M shorts (attn Q)   [0, 3.84M)
    short* lnbf   = (short*)(ws);             //   alias: LN out, after attn
    short* qbf    = (short*)(ws + 3840000);   // 7.68M shorts            [3.84M, 7.68M)
    short* kf_a   = (short*)(ws + 7680000);   // 1.92M shorts            [7.68M, 8.64M)
    short* kpbf   = (short*)(ws + 8640000);   // 1.92M shorts            [8.64M, 9.6M)
    short* vf_a   = (short*)(ws + 9600000);   // 1.92M shorts            [9.6M, 10.56M)
    short* vpbf   = (short*)(ws + 10560000);  // 1.92M shorts            [10.56M, 11.52M)
    float* add_q  = ws + 11520000;            // 1.28M fp32              [11.52M, 12.8M)
    float* attn_o = ws + 12800000;            // 7.68M fp32              [12.8M, 20.48M)
    short* xbf    = (short*)(ws + 12800000);  //   alias: 1.28M shorts   [12.8M, 13.44M)
    short* h1bf   = (short*)(ws + 13440000);  //   alias: 2.56M shorts   [13.44M, 14.72M)
    float* x      = ws + 20480000;            // 1.28M fp32              [20.48M, 21.76M)
    float* Zp     = ws + 21760000;            // 0.24M fp32              [21.76M, 22M)
    short* eW     = (short*)(ws + 22000000);  // early weights
    short* Wq_t    = eW;                      // 65,536
    short* Wk_t    = eW + 65536;
    short* Wv_t    = eW + 131072;
    short* Waddq_t = eW + 196608;             // 393,216
    short* lW     = (short*)(ws + 22295000);  // late weights
    short* Wproj_t = lW;                      // 393,216
    short* W1_t    = lW + 393216;             // 131,072
    short* W2_t    = lW + 524288;             // 131,072
    float* y2     = ws + 22625000;            // 1.28M fp32              [22.62M, 23.9M)

    dim3 blk(256);

    // early weights + activation prep
    {
        WtArgs a;
        a.j[0] = {Wq,    Wq_t,    256,  256};
        a.j[1] = {Wk,    Wk_t,    256,  256};
        a.j[2] = {Wv,    Wv_t,    256,  256};
        a.j[3] = {Waddq, Waddq_t, 1536, 256};
        wtconv<<<dim3(8, 48, 4), blk, 0, stream>>>(a);
    }
    prep<<<dim3(79, 8, 36), blk, 0, stream>>>(q, k, v, qbf, kpbf, vpbf);
    // input-side GEMMs (bf16 A, bf16 out)
    mgemm_bf<128, 0, 0, 1, 0><<<dim3(4, 235), blk, 0, stream>>>(
        qbf, Wq_t, bq, nullptr, nullptr, qf_a, 30000, 256, 256);
    mgemm_bf<64, 0, 0, 1, 0><<<dim3(4, 118), blk, 0, stream>>>(
        kpbf, Wk_t, bk, nullptr, nullptr, kf_a, 7500, 256, 256);
    mgemm_bf<64, 0, 0, 1, 0><<<dim3(4, 118), blk, 0, stream>>>(
        vpbf, Wv_t, bv, nullptr, nullptr, vf_a, 7500, 256, 256);
    mgemm_bf<64, 0, 1, 0, 1><<<dim3(4, 79), blk, 0, stream>>>(
        qbf, Waddq_t, baddq, nullptr, add_q, nullptr, 5000, 256, 1536);
    // late weights (own region; done before proj)
    {
        WtArgs a;
        a.j[0] = {Wproj, Wproj_t, 1536, 256};
        a.j[1] = {W1,    W1_t,    256,  512};
        a.j[2] = {W2,    W2_t,    512,  256};
        a.j[3] = {W2,    W2_t,    512,  256};   // dup, grid.z=3 never reaches
        wtconv<<<dim3(16, 48, 3), blk, 0, stream>>>(a);
    }
    // attention
    attn_mfma<<<dim3(40, 16, 6), blk, 0, stream>>>(qf_a, kf_a, vf_a, attn_o, Zp);
    // LN(1536) + softmax-normalize -> bf16 (into dead qf_a region)
    ln_pre_kernel<<<dim3(5000), blk, 0, stream>>>(attn_o, lnbf, Zp, g_pre, b_pre);
    // x = ln @ Wproj + bproj + add_q  (fp32 x + bf16 xbf)
    mgemm_bf<64, 2, 1, 1, 0><<<dim3(4, 79), blk, 0, stream>>>(
        lnbf, Wproj_t, bproj, add_q, x, xbf, 5000, 256, 1536);
    // h1 = gelu(x @ W1 + b1) -> bf16
    mgemm_bf<64, 1, 0, 1, 0><<<dim3(8, 79), blk, 0, stream>>>(
        xbf, W1_t, b1, nullptr, nullptr, h1bf, 5000, 512, 256);
    // y2 = h1 @ W2 + b2 -> fp32
    mgemm_bf<64, 0, 1, 0, 0><<<dim3(4, 79), blk, 0, stream>>>(
        h1bf, W2_t, b2, nullptr, y2, nullptr, 5000, 256, 512);
    final_kernel<<<dim3(5000), blk, 0, stream>>>(x, y2, g_nrm, b_nrm, out);
}

// Round 7
// 349.782 us; speedup vs baseline: 9.3743x; 1.0903x over previous
//
#include <hip/hip_runtime.h>
#include <math.h>

// Problem constants
#define BATCH 2
#define NCAM 6
#define DIM 256
#define HEADS 8
#define DH 32
#define HW 2500          // 50*50
#define KP 625           // 25*25 pooled keys per cam
#define NDIM (NCAM*DIM)  // 1536

typedef __attribute__((ext_vector_type(8))) short short8;
typedef __attribute__((ext_vector_type(4))) float f32x4;

__device__ __forceinline__ short f2bf(float f) {
    union { float f; unsigned u; } v; v.f = f;
    unsigned r = v.u + 0x7fffu + ((v.u >> 16) & 1u);   // round-to-nearest-even
    return (short)(r >> 16);
}
__device__ __forceinline__ float bf2f(short h) {
    union { unsigned u; float f; } v; v.u = ((unsigned)(unsigned short)h) << 16;
    return v.f;
}

// ---------------------------------------------------------------------------
// prep_all: ALL one-time data conversion in ONE launch.
//  blockIdx.x ranges:
//   [0, 7584)       q slab transpose   qbf[slab][hw][d] = bf16(q[slab][d][hw])
//   [7584, 9504)    k pool+transpose   kpbf[slab][kp][d]
//   [9504, 11424)   v pool+transpose   vpbf
//   [11424, 12640)  7 weight transpose jobs Wt[n][k] = bf16(W[k][n])
// ---------------------------------------------------------------------------
struct WJ { const float* src; short* dst; int K, N; };
struct WArgs { WJ j[7]; };

__global__ __launch_bounds__(256) void prep_all(
    const float* __restrict__ q, const float* __restrict__ k,
    const float* __restrict__ v, short* __restrict__ qbf,
    short* __restrict__ kpbf, short* __restrict__ vpbf, WArgs wa)
{
    __shared__ float t[32][33];
    const int tx = threadIdx.x & 31, ty = threadIdx.x >> 5;   // ty 0..7
    int i = blockIdx.x;
    if (i < 7584) {
        int slab = i / 632, rem = i % 632;
        int hwB = (rem % 79) * 32, dB = (rem / 79) * 32;
        const float* src = q + (size_t)slab * 640000;
#pragma unroll
        for (int ii = 0; ii < 32; ii += 8) {
            int hw = hwB + tx;
            t[ty + ii][tx] = (hw < HW) ? src[(size_t)(dB + ty + ii) * HW + hw] : 0.f;
        }
        __syncthreads();
#pragma unroll
        for (int ii = 0; ii < 32; ii += 8) {
            int hw = hwB + ty + ii;
            if (hw < HW)
                qbf[((size_t)slab * HW + hw) * DIM + dB + tx] = f2bf(t[tx][ty + ii]);
        }
    } else if (i < 11424) {
        int i2 = i - 7584;
        const float* base; short* dst;
        if (i2 < 1920) { base = k; dst = kpbf; }
        else           { base = v; dst = vpbf; i2 -= 1920; }
        int slab = i2 / 160, rem = i2 % 160;
        int kpB = (rem % 20) * 32, dB = (rem / 20) * 32;
        const float* src = base + (size_t)slab * 640000;
        dst += (size_t)slab * (KP * DIM);
#pragma unroll
        for (int ii = 0; ii < 32; ii += 8) {
            int kp = kpB + tx;
            float val = 0.f;
            if (kp < KP) {
                int r2 = (kp / 25) * 2, c2 = (kp % 25) * 2;
                const float* p0 = src + (size_t)(dB + ty + ii) * HW + r2 * 50 + c2;
                val = 0.25f * (p0[0] + p0[1] + p0[50] + p0[51]);
            }
            t[ty + ii][tx] = val;
        }
        __syncthreads();
#pragma unroll
        for (int ii = 0; ii < 32; ii += 8) {
            int kp = kpB + ty + ii;
            if (kp < KP)
                dst[(size_t)kp * DIM + dB + tx] = f2bf(t[tx][ty + ii]);
        }
    } else {
        int wi = i - 11424;
        WJ jb = wa.j[0];
        for (int jj = 0; jj < 7; jj++) {
            jb = wa.j[jj];
            int cnt = (jb.K >> 5) * (jb.N >> 5);
            if (wi < cnt) break;
            wi -= cnt;
        }
        int tn = jb.N >> 5;
        int nB = (wi % tn) * 32, kB = (wi / tn) * 32;
#pragma unroll
        for (int ii = 0; ii < 32; ii += 8)
            t[ty + ii][tx] = jb.src[(size_t)(kB + ty + ii) * jb.N + nB + tx];
        __syncthreads();
#pragma unroll
        for (int ii = 0; ii < 32; ii += 8)
            jb.dst[(size_t)(nB + ty + ii) * jb.K + kB + tx] = f2bf(t[tx][ty + ii]);
    }
}

// ---------------------------------------------------------------------------
// Batched input GEMMs (qf / kf / vf / add_q) in ONE launch. grid (4, 469, 4).
// BM=64, BN=64, BK=32; N=256 for all jobs. mode 1 = add_q row gather on qbf.
// Output bf16 (Cb) or fp32 (Cf).
// ---------------------------------------------------------------------------
struct GJob { const short* A; const short* Bt; const float* bias;
              short* Cb; float* Cf; int M, K, yb, mode; };
struct GArgs { GJob j[4]; };

__global__ __launch_bounds__(256) void gemm_in(GArgs ga) {
    GJob jb = ga.j[blockIdx.z];
    if ((int)blockIdx.y >= jb.yb) return;
    __shared__ short As[64 * 32];
    __shared__ short Bs[64 * 32];

    const int tid  = threadIdx.x;
    const int nB   = blockIdx.x * 64;
    const int rB   = blockIdx.y * 64;
    const int w    = tid >> 6;
    const int lane = tid & 63;
    const int l15  = lane & 15;
    const int quad = lane >> 4;
    const int M = jb.M, K = jb.K;

    f32x4 acc[4];
#pragma unroll
    for (int jt = 0; jt < 4; jt++) acc[jt] = (f32x4){0.f, 0.f, 0.f, 0.f};

    const int r = tid >> 2, gk = tid & 3;
    const int rg = rB + r;
    const int bb = rg / 2500, hwp = rg % 2500;   // for mode 1

    for (int kB = 0; kB < K; kB += 32) {
        __syncthreads();
        short8 a0 = {0, 0, 0, 0, 0, 0, 0, 0};
        if (rg < M) {
            if (jb.mode) {
                int kk = kB + gk * 8;
                int cam = kk >> 8, c = kk & 255;
                a0 = *(const short8*)&jb.A[(((size_t)(bb * 6 + cam)) * HW + hwp) * DIM + c];
            } else {
                a0 = *(const short8*)&jb.A[(size_t)rg * K + kB + gk * 8];
            }
        }
        *(short8*)&As[r * 32 + ((gk ^ (r & 3)) << 3)] = a0;
        short8 bv = *(const short8*)&jb.Bt[(size_t)(nB + r) * K + kB + gk * 8];
        *(short8*)&Bs[r * 32 + ((gk ^ (r & 3)) << 3)] = bv;
        __syncthreads();
        int m = w * 16 + l15;
        short8 af = *(const short8*)&As[m * 32 + ((quad ^ (m & 3)) << 3)];
#pragma unroll
        for (int jt = 0; jt < 4; jt++) {
            int n = jt * 16 + l15;
            short8 bfr = *(const short8*)&Bs[n * 32 + ((quad ^ (n & 3)) << 3)];
            acc[jt] = __builtin_amdgcn_mfma_f32_16x16x32_bf16(af, bfr, acc[jt], 0, 0, 0);
        }
    }
    int rbase = rB + w * 16 + quad * 4;
#pragma unroll
    for (int jt = 0; jt < 4; jt++) {
        int col = nB + jt * 16 + l15;
        float bcol = jb.bias[col];
#pragma unroll
        for (int reg = 0; reg < 4; reg++) {
            int rr = rbase + reg;
            if (rr < M) {
                float vv = acc[jt][reg] + bcol;
                if (jb.Cb) jb.Cb[(size_t)rr * 256 + col] = f2bf(vv);
                else       jb.Cf[(size_t)rr * 256 + col] = vv;
            }
        }
    }
}

// ---------------------------------------------------------------------------
// bf16-A MFMA GEMM for the tail (proj / W1 / W2). BM=64.
// EPI 0: bias; 1: bias+GELU; 2: bias+res.  WF32: fp32 C; WBF: bf16 C2.
// ---------------------------------------------------------------------------
template<int EPI, int WF32, int WBF>
__global__ __launch_bounds__(256) void mgemm_bf(
    const short* __restrict__ A, const short* __restrict__ Bt,
    const float* __restrict__ bias, const float* __restrict__ res,
    float* __restrict__ C, short* __restrict__ C2, int M, int N, int K)
{
    __shared__ short As[64 * 32];
    __shared__ short Bs[64 * 32];

    const int tid  = threadIdx.x;
    const int nB   = blockIdx.x * 64;
    const int rB   = blockIdx.y * 64;
    const int w    = tid >> 6;
    const int lane = tid & 63;
    const int l15  = lane & 15;
    const int quad = lane >> 4;

    f32x4 acc[4];
#pragma unroll
    for (int jt = 0; jt < 4; jt++) acc[jt] = (f32x4){0.f, 0.f, 0.f, 0.f};

    const int r = tid >> 2, gk = tid & 3;
    const int rg = rB + r;

    for (int kB = 0; kB < K; kB += 32) {
        __syncthreads();
        short8 a0 = {0, 0, 0, 0, 0, 0, 0, 0};
        if (rg < M) a0 = *(const short8*)&A[(size_t)rg * K + kB + gk * 8];
        *(short8*)&As[r * 32 + ((gk ^ (r & 3)) << 3)] = a0;
        short8 bv = *(const short8*)&Bt[(size_t)(nB + r) * K + kB + gk * 8];
        *(short8*)&Bs[r * 32 + ((gk ^ (r & 3)) << 3)] = bv;
        __syncthreads();
        int m = w * 16 + l15;
        short8 af = *(const short8*)&As[m * 32 + ((quad ^ (m & 3)) << 3)];
#pragma unroll
        for (int jt = 0; jt < 4; jt++) {
            int n = jt * 16 + l15;
            short8 bfr = *(const short8*)&Bs[n * 32 + ((quad ^ (n & 3)) << 3)];
            acc[jt] = __builtin_amdgcn_mfma_f32_16x16x32_bf16(af, bfr, acc[jt], 0, 0, 0);
        }
    }
    int rbase = rB + w * 16 + quad * 4;
#pragma unroll
    for (int jt = 0; jt < 4; jt++) {
        int col = nB + jt * 16 + l15;
        float bcol = bias[col];
#pragma unroll
        for (int reg = 0; reg < 4; reg++) {
            int rr = rbase + reg;
            if (rr < M) {
                float vv = acc[jt][reg] + bcol;
                if (EPI == 1) vv = 0.5f * vv * (1.f + erff(vv * 0.70710678118654752f));
                if (EPI == 2) vv += res[(size_t)rr * N + col];
                if (WF32) C[(size_t)rr * N + col] = vv;
                if (WBF)  C2[(size_t)rr * N + col] = f2bf(vv);
            }
        }
    }
}

// ---------------------------------------------------------------------------
// MFMA attention (unchanged from R4): block = 64 queries x (b,m,cam).
// ---------------------------------------------------------------------------
#define TQA 64
#define CH 64
#define VSTR 72

__global__ __launch_bounds__(256) void attn_mfma(
    const short* __restrict__ qf, const short* __restrict__ kf,
    const short* __restrict__ vf, float* __restrict__ attn_out,
    float* __restrict__ Zp)
{
    const int qt  = blockIdx.x;
    const int bm  = blockIdx.y;
    const int cam = blockIdx.z;
    const int b = bm >> 3, m = bm & 7;
    const int q0 = qt * TQA;
    const int tid = threadIdx.x;
    const int w = tid >> 6, lane = tid & 63;
    const int l15 = lane & 15, quad = lane >> 4;

    __shared__ __align__(16) short Ks[CH][DH];
    __shared__ __align__(16) short Vt[DH][VSTR];
    __shared__ __align__(16) short Pl[TQA][VSTR];

    const size_t slab = (size_t)(b * 6 + cam);

    int qrow = q0 + w * 16 + l15;
    int qcl  = qrow < HW ? qrow : HW - 1;
    const short8 aq = *(const short8*)&qf[(slab * HW + qcl) * DIM + m * DH + quad * 8];

    const short* kb = kf + slab * KP * DIM + m * DH;
    const short* vb = vf + slab * KP * DIM + m * DH;

    f32x4 oacc[2];
    oacc[0] = (f32x4){0.f, 0.f, 0.f, 0.f};
    oacc[1] = (f32x4){0.f, 0.f, 0.f, 0.f};
    float zp[4] = {0.f, 0.f, 0.f, 0.f};
    const float scale = 0.17677669529663687f;

    const int kl = tid >> 2, d8 = (tid & 3) * 8;
    const int vcol = (((kl >> 3) ^ (d8 >> 3)) << 3) | (kl & 7);

    for (int c0 = 0; c0 < KP; c0 += CH) {
        __syncthreads();
        {
            int key = c0 + kl;
            short8 kv8 = {0, 0, 0, 0, 0, 0, 0, 0};
            short8 vv8 = {0, 0, 0, 0, 0, 0, 0, 0};
            if (key < KP) {
                kv8 = *(const short8*)&kb[(size_t)key * DIM + d8];
                vv8 = *(const short8*)&vb[(size_t)key * DIM + d8];
            }
            *(short8*)&Ks[kl][d8] = kv8;
#pragma unroll
            for (int t = 0; t < 8; t++) Vt[d8 + t][vcol] = vv8[t];
        }
        __syncthreads();
        f32x4 sfrag[4];
#pragma unroll
        for (int jt = 0; jt < 4; jt++) {
            short8 bk8 = *(const short8*)&Ks[jt * 16 + l15][quad * 8];
            sfrag[jt] = __builtin_amdgcn_mfma_f32_16x16x32_bf16(
                aq, bk8, (f32x4){0.f, 0.f, 0.f, 0.f}, 0, 0, 0);
        }
#pragma unroll
        for (int jt = 0; jt < 4; jt++) {
            bool valid = (c0 + jt * 16 + l15) < KP;
#pragma unroll
            for (int reg = 0; reg < 4; reg++) {
                float p = valid ? __expf(scale * sfrag[jt][reg]) : 0.f;
                short ph = f2bf(p);
                zp[reg] += bf2f(ph);
                Pl[w * 16 + quad * 4 + reg][jt * 16 + l15] = ph;
            }
        }
#pragma unroll
        for (int ks = 0; ks < 2; ks++) {
            short8 ap = *(const short8*)&Pl[w * 16 + l15][ks * 32 + quad * 8];
#pragma unroll
            for (int nt = 0; nt < 2; nt++) {
                int dhn = nt * 16 + l15;
                int pgrp = ((ks * 4 + quad) ^ (dhn >> 3));
                short8 bv8 = *(const short8*)&Vt[dhn][pgrp << 3];
                oacc[nt] = __builtin_amdgcn_mfma_f32_16x16x32_bf16(
                    ap, bv8, oacc[nt], 0, 0, 0);
            }
        }
    }
#pragma unroll
    for (int off = 1; off < 16; off <<= 1)
#pragma unroll
        for (int reg = 0; reg < 4; reg++)
            zp[reg] += __shfl_xor(zp[reg], off, 64);
#pragma unroll
    for (int reg = 0; reg < 4; reg++) {
        int q = q0 + w * 16 + quad * 4 + reg;
        if (q < HW) {
            size_t rowb = ((size_t)b * HW + q) * NDIM + cam * DIM + m * DH;
            attn_out[rowb + l15]      = oacc[0][reg];
            attn_out[rowb + 16 + l15] = oacc[1][reg];
            if (l15 == 0)
                Zp[((size_t)bm * 6 + cam) * HW + q] = zp[reg];
        }
    }
}

// ---------------------------------------------------------------------------
// LayerNorm over 1536 + fused joint-softmax normalization; writes bf16.
// ---------------------------------------------------------------------------
__global__ __launch_bounds__(256) void ln_pre_kernel(
    const float* __restrict__ xin, short* __restrict__ lnbf,
    const float* __restrict__ Zp,
    const float* __restrict__ g, const float* __restrict__ bt)
{
    const int row = blockIdx.x;
    const int tid = threadIdx.x;
    const int b = row / 2500, q = row % 2500;
    __shared__ float zinv[8];
    if (tid < 8) {
        float z = 0.f;
#pragma unroll
        for (int cam = 0; cam < 6; cam++)
            z += Zp[((size_t)(b * 8 + tid) * 6 + cam) * HW + q];
        zinv[tid] = 1.f / z;
    }
    __syncthreads();
    const float* p = xin + (size_t)row * NDIM;
    float v[6];
    float s = 0.f, ss = 0.f;
#pragma unroll
    for (int i = 0; i < 6; i++) {
        int c = tid + i * 256;
        v[i] = p[c] * zinv[(c >> 5) & 7];
        s += v[i]; ss += v[i] * v[i];
    }
    __shared__ float rs[4], rss[4];
    int lane = tid & 63, wid = tid >> 6;
#pragma unroll
    for (int o = 32; o > 0; o >>= 1) { s += __shfl_down(s, o); ss += __shfl_down(ss, o); }
    if (lane == 0) { rs[wid] = s; rss[wid] = ss; }
    __syncthreads();
    s = rs[0] + rs[1] + rs[2] + rs[3];
    ss = rss[0] + rss[1] + rss[2] + rss[3];
    float mu = s * (1.f / NDIM);
    float var = ss * (1.f / NDIM) - mu * mu;
    float inv = rsqrtf(var + 1e-5f);
#pragma unroll
    for (int i = 0; i < 6; i++) {
        int c = tid + i * 256;
        lnbf[(size_t)row * NDIM + c] = f2bf((v[i] - mu) * inv * g[c] + bt[c]);
    }
}

// ---------------------------------------------------------------------------
// final2: out[b,c,hw] = x[row,c] + LN256(y2[row])*g + b, with LDS transpose
// so global stores are hw-contiguous. 32 rows/block, grid 157.
// Thread map (LN phase): rl = tid&31 (row), seg = tid>>5 (32-col segment).
// Store phase: wave w stores c = it*8 + w*2 + (lane>>5), hw = r0 + (lane&31)
// -> two 128 B contiguous runs per wave-instruction.
// ---------------------------------------------------------------------------
__global__ __launch_bounds__(256) void final_kernel2(
    const float* __restrict__ x, const float* __restrict__ y2,
    const float* __restrict__ g, const float* __restrict__ bt,
    float* __restrict__ out)
{
    __shared__ float T[256][33];    // [c][row_local]
    __shared__ float ps[32][8], pss[32][8];
    __shared__ float mu_s[32], inv_s[32];
    const int tid = threadIdx.x;
    const int rl = tid & 31, seg = tid >> 5;
    const int r0 = blockIdx.x * 32;
    const int row = r0 + rl;
    const bool ok = row < 5000;

    float4 yv[8];
    float s = 0.f, ss = 0.f;
    if (ok) {
        const float4* yp = (const float4*)(y2 + (size_t)row * DIM + seg * 32);
#pragma unroll
        for (int j = 0; j < 8; j++) {
            yv[j] = yp[j];
            s += yv[j].x + yv[j].y + yv[j].z + yv[j].w;
            ss += yv[j].x * yv[j].x + yv[j].y * yv[j].y
                + yv[j].z * yv[j].z + yv[j].w * yv[j].w;
        }
    } else {
#pragma unroll
        for (int j = 0; j < 8; j++) yv[j] = (float4){0, 0, 0, 0};
    }
    ps[rl][seg] = s; pss[rl][seg] = ss;
    __syncthreads();
    if (tid < 32) {
        float a = 0.f, b2 = 0.f;
#pragma unroll
        for (int j = 0; j < 8; j++) { a += ps[tid][j]; b2 += pss[tid][j]; }
        float mu = a * (1.f / DIM);
        float var = b2 * (1.f / DIM) - mu * mu;
        mu_s[tid] = mu;
        inv_s[tid] = rsqrtf(var + 1e-5f);
    }
    __syncthreads();
    if (ok) {
        float mu = mu_s[rl], inv = inv_s[rl];
        const float4* xp = (const float4*)(x + (size_t)row * DIM + seg * 32);
#pragma unroll
        for (int j = 0; j < 8; j++) {
            float4 xv = xp[j];
            int c = seg * 32 + j * 4;
            T[c + 0][rl] = xv.x + (yv[j].x - mu) * inv * g[c + 0] + bt[c + 0];
            T[c + 1][rl] = xv.y + (yv[j].y - mu) * inv * g[c + 1] + bt[c + 1];
            T[c + 2][rl] = xv.z + (yv[j].z - mu) * inv * g[c + 2] + bt[c + 2];
            T[c + 3][rl] = xv.w + (yv[j].w - mu) * inv * g[c + 3] + bt[c + 3];
        }
    }
    __syncthreads();
    const int w = tid >> 6, lane = tid & 63;
    const int hl = lane & 31, ch = lane >> 5;
    const int rr = r0 + hl;
    if (rr < 5000) {
        int b = rr / 2500, hw = rr % 2500;
        size_t obase = (size_t)b * 640000 + hw;
#pragma unroll
        for (int it = 0; it < 32; it++) {
            int c = it * 8 + w * 2 + ch;
            out[obase + (size_t)c * 2500] = T[c][hl];
        }
    }
}

// ---------------------------------------------------------------------------
extern "C" void kernel_launch(void* const* d_in, const int* in_sizes, int n_in,
                              void* d_out, int out_size, void* d_ws, size_t ws_size,
                              hipStream_t stream)
{
    const float* q     = (const float*)d_in[0];
    const float* k     = (const float*)d_in[1];
    const float* v     = (const float*)d_in[2];
    const float* Wq    = (const float*)d_in[3];
    const float* bq    = (const float*)d_in[4];
    const float* Wk    = (const float*)d_in[5];
    const float* bk    = (const float*)d_in[6];
    const float* Wv    = (const float*)d_in[7];
    const float* bv    = (const float*)d_in[8];
    const float* Wproj = (const float*)d_in[9];
    const float* bproj = (const float*)d_in[10];
    const float* Waddq = (const float*)d_in[11];
    const float* baddq = (const float*)d_in[12];
    const float* W1    = (const float*)d_in[13];
    const float* b1    = (const float*)d_in[14];
    const float* W2    = (const float*)d_in[15];
    const float* b2    = (const float*)d_in[16];
    const float* g_pre = (const float*)d_in[17];
    const float* b_pre = (const float*)d_in[18];
    const float* g_nrm = (const float*)d_in[19];
    const float* b_nrm = (const float*)d_in[20];
    float* out = (float*)d_out;

    // workspace layout (float-unit offsets) — as R6
    float* ws = (float*)d_ws;
    short* qf_a   = (short*)(ws);             // [0, 3.84M)
    short* lnbf   = (short*)(ws);             //   alias after attn
    short* qbf    = (short*)(ws + 3840000);   // [3.84M, 7.68M)
    short* kf_a   = (short*)(ws + 7680000);   // [7.68M, 8.64M)
    short* kpbf   = (short*)(ws + 8640000);   // [8.64M, 9.6M)
    short* vf_a   = (short*)(ws + 9600000);   // [9.6M, 10.56M)
    short* vpbf   = (short*)(ws + 10560000);  // [10.56M, 11.52M)
    float* add_q  = ws + 11520000;            // [11.52M, 12.8M)
    float* attn_o = ws + 12800000;            // [12.8M, 20.48M)
    short* xbf    = (short*)(ws + 12800000);  //   alias: [12.8M, 13.44M)
    short* h1bf   = (short*)(ws + 13440000);  //   alias: [13.44M, 14.72M)
    float* x      = ws + 20480000;            // [20.48M, 21.76M)
    float* Zp     = ws + 21760000;            // [21.76M, 22M)
    short* eW     = (short*)(ws + 22000000);
    short* Wq_t    = eW;
    short* Wk_t    = eW + 65536;
    short* Wv_t    = eW + 131072;
    short* Waddq_t = eW + 196608;
    short* lW     = (short*)(ws + 22295000);
    short* Wproj_t = lW;
    short* W1_t    = lW + 393216;
    short* W2_t    = lW + 524288;
    float* y2     = ws + 22625000;            // [22.62M, 23.9M)

    dim3 blk(256);

    // 1) all conversion work in one launch
    {
        WArgs wa;
        wa.j[0] = {Wq,    Wq_t,    256,  256};
        wa.j[1] = {Wk,    Wk_t,    256,  256};
        wa.j[2] = {Wv,    Wv_t,    256,  256};
        wa.j[3] = {Waddq, Waddq_t, 1536, 256};
        wa.j[4] = {Wproj, Wproj_t, 1536, 256};
        wa.j[5] = {W1,    W1_t,    256,  512};
        wa.j[6] = {W2,    W2_t,    512,  256};
        prep_all<<<dim3(12640), blk, 0, stream>>>(q, k, v, qbf, kpbf, vpbf, wa);
    }
    // 2) all input-side GEMMs in one launch
    {
        GArgs ga;
        ga.j[0] = {qbf,  Wq_t,    bq,    qf_a, nullptr, 30000, 256,  469, 0};
        ga.j[1] = {kpbf, Wk_t,    bk,    kf_a, nullptr, 7500,  256,  118, 0};
        ga.j[2] = {vpbf, Wv_t,    bv,    vf_a, nullptr, 7500,  256,  118, 0};
        ga.j[3] = {qbf,  Waddq_t, baddq, nullptr, add_q, 5000, 1536, 79,  1};
        gemm_in<<<dim3(4, 469, 4), blk, 0, stream>>>(ga);
    }
    // 3) attention
    attn_mfma<<<dim3(40, 16, 6), blk, 0, stream>>>(qf_a, kf_a, vf_a, attn_o, Zp);
    // 4) LN(1536) + softmax-normalize -> bf16 (into dead qf_a region)
    ln_pre_kernel<<<dim3(5000), blk, 0, stream>>>(attn_o, lnbf, Zp, g_pre, b_pre);
    // 5) x = ln @ Wproj + bproj + add_q  (fp32 x + bf16 xbf)
    mgemm_bf<2, 1, 1><<<dim3(4, 79), blk, 0, stream>>>(
        lnbf, Wproj_t, bproj, add_q, x, xbf, 5000, 256, 1536);
    // 6) h1 = gelu(x @ W1 + b1) -> bf16
    mgemm_bf<1, 0, 1><<<dim3(8, 79), blk, 0, stream>>>(
        xbf, W1_t, b1, nullptr, nullptr, h1bf, 5000, 512, 256);
    // 7) y2 = h1 @ W2 + b2 -> fp32
    mgemm_bf<0, 1, 0><<<dim3(4, 79), blk, 0, stream>>>(
        h1bf, W2_t, b2, nullptr, y2, nullptr, 5000, 256, 512);
    // 8) out = transpose(x + LN256(y2)) — coalesced
    final_kernel2<<<dim3(157), blk, 0, stream>>>(x, y2, g_nrm, b_nrm, out);
}

// Round 8
// 342.776 us; speedup vs baseline: 9.5659x; 1.0204x over previous
//
#include <hip/hip_runtime.h>
#include <math.h>

// Problem constants
#define BATCH 2
#define NCAM 6
#define DIM 256
#define HEADS 8
#define DH 32
#define HW 2500          // 50*50
#define KP 625           // 25*25 pooled keys per cam
#define NDIM (NCAM*DIM)  // 1536

typedef __attribute__((ext_vector_type(8))) short short8;
typedef __attribute__((ext_vector_type(4))) float f32x4;

__device__ __forceinline__ short f2bf(float f) {
    union { float f; unsigned u; } v; v.f = f;
    unsigned r = v.u + 0x7fffu + ((v.u >> 16) & 1u);   // round-to-nearest-even
    return (short)(r >> 16);
}
__device__ __forceinline__ float bf2f(short h) {
    union { unsigned u; float f; } v; v.u = ((unsigned)(unsigned short)h) << 16;
    return v.f;
}

// ---------------------------------------------------------------------------
// prep_all: ALL one-time data conversion in ONE launch (as R7).
// ---------------------------------------------------------------------------
struct WJ { const float* src; short* dst; int K, N; };
struct WArgs { WJ j[7]; };

__global__ __launch_bounds__(256) void prep_all(
    const float* __restrict__ q, const float* __restrict__ k,
    const float* __restrict__ v, short* __restrict__ qbf,
    short* __restrict__ kpbf, short* __restrict__ vpbf, WArgs wa)
{
    __shared__ float t[32][33];
    const int tx = threadIdx.x & 31, ty = threadIdx.x >> 5;   // ty 0..7
    int i = blockIdx.x;
    if (i < 7584) {
        int slab = i / 632, rem = i % 632;
        int hwB = (rem % 79) * 32, dB = (rem / 79) * 32;
        const float* src = q + (size_t)slab * 640000;
#pragma unroll
        for (int ii = 0; ii < 32; ii += 8) {
            int hw = hwB + tx;
            t[ty + ii][tx] = (hw < HW) ? src[(size_t)(dB + ty + ii) * HW + hw] : 0.f;
        }
        __syncthreads();
#pragma unroll
        for (int ii = 0; ii < 32; ii += 8) {
            int hw = hwB + ty + ii;
            if (hw < HW)
                qbf[((size_t)slab * HW + hw) * DIM + dB + tx] = f2bf(t[tx][ty + ii]);
        }
    } else if (i < 11424) {
        int i2 = i - 7584;
        const float* base; short* dst;
        if (i2 < 1920) { base = k; dst = kpbf; }
        else           { base = v; dst = vpbf; i2 -= 1920; }
        int slab = i2 / 160, rem = i2 % 160;
        int kpB = (rem % 20) * 32, dB = (rem / 20) * 32;
        const float* src = base + (size_t)slab * 640000;
        dst += (size_t)slab * (KP * DIM);
#pragma unroll
        for (int ii = 0; ii < 32; ii += 8) {
            int kp = kpB + tx;
            float val = 0.f;
            if (kp < KP) {
                int r2 = (kp / 25) * 2, c2 = (kp % 25) * 2;
                const float* p0 = src + (size_t)(dB + ty + ii) * HW + r2 * 50 + c2;
                val = 0.25f * (p0[0] + p0[1] + p0[50] + p0[51]);
            }
            t[ty + ii][tx] = val;
        }
        __syncthreads();
#pragma unroll
        for (int ii = 0; ii < 32; ii += 8) {
            int kp = kpB + ty + ii;
            if (kp < KP)
                dst[(size_t)kp * DIM + dB + tx] = f2bf(t[tx][ty + ii]);
        }
    } else {
        int wi = i - 11424;
        WJ jb = wa.j[0];
        for (int jj = 0; jj < 7; jj++) {
            jb = wa.j[jj];
            int cnt = (jb.K >> 5) * (jb.N >> 5);
            if (wi < cnt) break;
            wi -= cnt;
        }
        int tn = jb.N >> 5;
        int nB = (wi % tn) * 32, kB = (wi / tn) * 32;
#pragma unroll
        for (int ii = 0; ii < 32; ii += 8)
            t[ty + ii][tx] = jb.src[(size_t)(kB + ty + ii) * jb.N + nB + tx];
        __syncthreads();
#pragma unroll
        for (int ii = 0; ii < 32; ii += 8)
            jb.dst[(size_t)(nB + ty + ii) * jb.K + kB + tx] = f2bf(t[tx][ty + ii]);
    }
}

// ---------------------------------------------------------------------------
// Batched input GEMMs, BM=128 (RT=2) + register-prefetch double buffering.
// grid (4, 235, 4). mode 1 = add_q row gather on qbf.
// Per wave per BK=32: 8 MFMA vs 6 ds_read_b128 -> ~80% LDS-BW ceiling
// (vs 48% at BM=64).
// ---------------------------------------------------------------------------
struct GJob { const short* A; const short* Bt; const float* bias;
              short* Cb; float* Cf; int M, K, yb, mode; };
struct GArgs { GJob j[4]; };

__global__ __launch_bounds__(256) void gemm_in(GArgs ga) {
    GJob jb = ga.j[blockIdx.z];
    if ((int)blockIdx.y >= jb.yb) return;
    __shared__ short As[128 * 32];
    __shared__ short Bs[64 * 32];

    const int tid  = threadIdx.x;
    const int nB   = blockIdx.x * 64;
    const int rB   = blockIdx.y * 128;
    const int w    = tid >> 6;
    const int lane = tid & 63;
    const int l15  = lane & 15;
    const int quad = lane >> 4;
    const int M = jb.M, K = jb.K;

    f32x4 acc[2][4];
#pragma unroll
    for (int i = 0; i < 2; i++)
#pragma unroll
        for (int jt = 0; jt < 4; jt++) acc[i][jt] = (f32x4){0.f, 0.f, 0.f, 0.f};

    const int ra = tid >> 1, k0 = (tid & 1) * 16;   // A staging
    const int rga = rB + ra;
    const int bb = rga / 2500, hwp = rga % 2500;    // mode 1 row decode
    const int nb_ = tid >> 2, gkb = tid & 3;        // B staging

    short8 pa0 = {0,0,0,0,0,0,0,0}, pa1 = pa0, pb = pa0;
    // prologue: prefetch kB=0
    if (rga < M) {
        if (jb.mode) {
            int cam = k0 >> 8, c = k0 & 255;
            const short* p = &jb.A[(((size_t)(bb * 6 + cam)) * HW + hwp) * DIM + c];
            pa0 = *(const short8*)p; pa1 = *(const short8*)(p + 8);
        } else {
            const short* p = &jb.A[(size_t)rga * K + k0];
            pa0 = *(const short8*)p; pa1 = *(const short8*)(p + 8);
        }
    }
    pb = *(const short8*)&jb.Bt[(size_t)(nB + nb_) * K + gkb * 8];

    for (int kB = 0; kB < K; kB += 32) {
        __syncthreads();
        {
            int g0 = k0 >> 3;
            *(short8*)&As[ra * 32 + ((g0 ^ (ra & 3)) << 3)]       = pa0;
            *(short8*)&As[ra * 32 + (((g0 + 1) ^ (ra & 3)) << 3)] = pa1;
            *(short8*)&Bs[nb_ * 32 + ((gkb ^ (nb_ & 3)) << 3)]    = pb;
        }
        __syncthreads();
        // prefetch next tile while MFMAs run
        int kN = kB + 32;
        if (kN < K) {
            if (rga < M) {
                if (jb.mode) {
                    int kk = kN + k0;
                    int cam = kk >> 8, c = kk & 255;
                    const short* p = &jb.A[(((size_t)(bb * 6 + cam)) * HW + hwp) * DIM + c];
                    pa0 = *(const short8*)p; pa1 = *(const short8*)(p + 8);
                } else {
                    const short* p = &jb.A[(size_t)rga * K + kN + k0];
                    pa0 = *(const short8*)p; pa1 = *(const short8*)(p + 8);
                }
            }
            pb = *(const short8*)&jb.Bt[(size_t)(nB + nb_) * K + kN + gkb * 8];
        }
        short8 af[2], bfr[4];
#pragma unroll
        for (int i = 0; i < 2; i++) {
            int m = w * 32 + i * 16 + l15;
            af[i] = *(const short8*)&As[m * 32 + ((quad ^ (m & 3)) << 3)];
        }
#pragma unroll
        for (int jt = 0; jt < 4; jt++) {
            int n = jt * 16 + l15;
            bfr[jt] = *(const short8*)&Bs[n * 32 + ((quad ^ (n & 3)) << 3)];
        }
#pragma unroll
        for (int i = 0; i < 2; i++)
#pragma unroll
            for (int jt = 0; jt < 4; jt++)
                acc[i][jt] = __builtin_amdgcn_mfma_f32_16x16x32_bf16(
                    af[i], bfr[jt], acc[i][jt], 0, 0, 0);
    }
#pragma unroll
    for (int i = 0; i < 2; i++) {
        int rbase = rB + w * 32 + i * 16 + quad * 4;
#pragma unroll
        for (int jt = 0; jt < 4; jt++) {
            int col = nB + jt * 16 + l15;
            float bcol = jb.bias[col];
#pragma unroll
            for (int reg = 0; reg < 4; reg++) {
                int rr = rbase + reg;
                if (rr < M) {
                    float vv = acc[i][jt][reg] + bcol;
                    if (jb.Cb) jb.Cb[(size_t)rr * 256 + col] = f2bf(vv);
                    else       jb.Cf[(size_t)rr * 256 + col] = vv;
                }
            }
        }
    }
}

// ---------------------------------------------------------------------------
// Tail GEMM, BM=128 (RT=2) + register-prefetch dbuf.
// EPI 0: bias; 1: bias+GELU; 2: bias+res.  WF32: fp32 C; WBF: bf16 C2.
// ---------------------------------------------------------------------------
template<int EPI, int WF32, int WBF>
__global__ __launch_bounds__(256) void mgemm_bf(
    const short* __restrict__ A, const short* __restrict__ Bt,
    const float* __restrict__ bias, const float* __restrict__ res,
    float* __restrict__ C, short* __restrict__ C2, int M, int N, int K)
{
    __shared__ short As[128 * 32];
    __shared__ short Bs[64 * 32];

    const int tid  = threadIdx.x;
    const int nB   = blockIdx.x * 64;
    const int rB   = blockIdx.y * 128;
    const int w    = tid >> 6;
    const int lane = tid & 63;
    const int l15  = lane & 15;
    const int quad = lane >> 4;

    f32x4 acc[2][4];
#pragma unroll
    for (int i = 0; i < 2; i++)
#pragma unroll
        for (int jt = 0; jt < 4; jt++) acc[i][jt] = (f32x4){0.f, 0.f, 0.f, 0.f};

    const int ra = tid >> 1, k0 = (tid & 1) * 16;
    const int rga = rB + ra;
    const int nb_ = tid >> 2, gkb = tid & 3;

    short8 pa0 = {0,0,0,0,0,0,0,0}, pa1 = pa0, pb = pa0;
    if (rga < M) {
        const short* p = &A[(size_t)rga * K + k0];
        pa0 = *(const short8*)p; pa1 = *(const short8*)(p + 8);
    }
    pb = *(const short8*)&Bt[(size_t)(nB + nb_) * K + gkb * 8];

    for (int kB = 0; kB < K; kB += 32) {
        __syncthreads();
        {
            int g0 = k0 >> 3;
            *(short8*)&As[ra * 32 + ((g0 ^ (ra & 3)) << 3)]       = pa0;
            *(short8*)&As[ra * 32 + (((g0 + 1) ^ (ra & 3)) << 3)] = pa1;
            *(short8*)&Bs[nb_ * 32 + ((gkb ^ (nb_ & 3)) << 3)]    = pb;
        }
        __syncthreads();
        int kN = kB + 32;
        if (kN < K) {
            if (rga < M) {
                const short* p = &A[(size_t)rga * K + kN + k0];
                pa0 = *(const short8*)p; pa1 = *(const short8*)(p + 8);
            }
            pb = *(const short8*)&Bt[(size_t)(nB + nb_) * K + kN + gkb * 8];
        }
        short8 af[2], bfr[4];
#pragma unroll
        for (int i = 0; i < 2; i++) {
            int m = w * 32 + i * 16 + l15;
            af[i] = *(const short8*)&As[m * 32 + ((quad ^ (m & 3)) << 3)];
        }
#pragma unroll
        for (int jt = 0; jt < 4; jt++) {
            int n = jt * 16 + l15;
            bfr[jt] = *(const short8*)&Bs[n * 32 + ((quad ^ (n & 3)) << 3)];
        }
#pragma unroll
        for (int i = 0; i < 2; i++)
#pragma unroll
            for (int jt = 0; jt < 4; jt++)
                acc[i][jt] = __builtin_amdgcn_mfma_f32_16x16x32_bf16(
                    af[i], bfr[jt], acc[i][jt], 0, 0, 0);
    }
#pragma unroll
    for (int i = 0; i < 2; i++) {
        int rbase = rB + w * 32 + i * 16 + quad * 4;
#pragma unroll
        for (int jt = 0; jt < 4; jt++) {
            int col = nB + jt * 16 + l15;
            float bcol = bias[col];
#pragma unroll
            for (int reg = 0; reg < 4; reg++) {
                int rr = rbase + reg;
                if (rr < M) {
                    float vv = acc[i][jt][reg] + bcol;
                    if (EPI == 1) vv = 0.5f * vv * (1.f + erff(vv * 0.70710678118654752f));
                    if (EPI == 2) vv += res[(size_t)rr * N + col];
                    if (WF32) C[(size_t)rr * N + col] = vv;
                    if (WBF)  C2[(size_t)rr * N + col] = f2bf(vv);
                }
            }
        }
    }
}

// ---------------------------------------------------------------------------
// MFMA attention — as R4/R7 but attn_out is now bf16 (halves write traffic).
// ---------------------------------------------------------------------------
#define TQA 64
#define CH 64
#define VSTR 72

__global__ __launch_bounds__(256) void attn_mfma(
    const short* __restrict__ qf, const short* __restrict__ kf,
    const short* __restrict__ vf, short* __restrict__ attn_out,
    float* __restrict__ Zp)
{
    const int qt  = blockIdx.x;
    const int bm  = blockIdx.y;
    const int cam = blockIdx.z;
    const int b = bm >> 3, m = bm & 7;
    const int q0 = qt * TQA;
    const int tid = threadIdx.x;
    const int w = tid >> 6, lane = tid & 63;
    const int l15 = lane & 15, quad = lane >> 4;

    __shared__ __align__(16) short Ks[CH][DH];
    __shared__ __align__(16) short Vt[DH][VSTR];
    __shared__ __align__(16) short Pl[TQA][VSTR];

    const size_t slab = (size_t)(b * 6 + cam);

    int qrow = q0 + w * 16 + l15;
    int qcl  = qrow < HW ? qrow : HW - 1;
    const short8 aq = *(const short8*)&qf[(slab * HW + qcl) * DIM + m * DH + quad * 8];

    const short* kb = kf + slab * KP * DIM + m * DH;
    const short* vb = vf + slab * KP * DIM + m * DH;

    f32x4 oacc[2];
    oacc[0] = (f32x4){0.f, 0.f, 0.f, 0.f};
    oacc[1] = (f32x4){0.f, 0.f, 0.f, 0.f};
    float zp[4] = {0.f, 0.f, 0.f, 0.f};
    const float scale = 0.17677669529663687f;

    const int kl = tid >> 2, d8 = (tid & 3) * 8;
    const int vcol = (((kl >> 3) ^ (d8 >> 3)) << 3) | (kl & 7);

    for (int c0 = 0; c0 < KP; c0 += CH) {
        __syncthreads();
        {
            int key = c0 + kl;
            short8 kv8 = {0, 0, 0, 0, 0, 0, 0, 0};
            short8 vv8 = {0, 0, 0, 0, 0, 0, 0, 0};
            if (key < KP) {
                kv8 = *(const short8*)&kb[(size_t)key * DIM + d8];
                vv8 = *(const short8*)&vb[(size_t)key * DIM + d8];
            }
            *(short8*)&Ks[kl][d8] = kv8;
#pragma unroll
            for (int t = 0; t < 8; t++) Vt[d8 + t][vcol] = vv8[t];
        }
        __syncthreads();
        f32x4 sfrag[4];
#pragma unroll
        for (int jt = 0; jt < 4; jt++) {
            short8 bk8 = *(const short8*)&Ks[jt * 16 + l15][quad * 8];
            sfrag[jt] = __builtin_amdgcn_mfma_f32_16x16x32_bf16(
                aq, bk8, (f32x4){0.f, 0.f, 0.f, 0.f}, 0, 0, 0);
        }
#pragma unroll
        for (int jt = 0; jt < 4; jt++) {
            bool valid = (c0 + jt * 16 + l15) < KP;
#pragma unroll
            for (int reg = 0; reg < 4; reg++) {
                float p = valid ? __expf(scale * sfrag[jt][reg]) : 0.f;
                short ph = f2bf(p);
                zp[reg] += bf2f(ph);
                Pl[w * 16 + quad * 4 + reg][jt * 16 + l15] = ph;
            }
        }
#pragma unroll
        for (int ks = 0; ks < 2; ks++) {
            short8 ap = *(const short8*)&Pl[w * 16 + l15][ks * 32 + quad * 8];
#pragma unroll
            for (int nt = 0; nt < 2; nt++) {
                int dhn = nt * 16 + l15;
                int pgrp = ((ks * 4 + quad) ^ (dhn >> 3));
                short8 bv8 = *(const short8*)&Vt[dhn][pgrp << 3];
                oacc[nt] = __builtin_amdgcn_mfma_f32_16x16x32_bf16(
                    ap, bv8, oacc[nt], 0, 0, 0);
            }
        }
    }
#pragma unroll
    for (int off = 1; off < 16; off <<= 1)
#pragma unroll
        for (int reg = 0; reg < 4; reg++)
            zp[reg] += __shfl_xor(zp[reg], off, 64);
#pragma unroll
    for (int reg = 0; reg < 4; reg++) {
        int q = q0 + w * 16 + quad * 4 + reg;
        if (q < HW) {
            size_t rowb = ((size_t)b * HW + q) * NDIM + cam * DIM + m * DH;
            attn_out[rowb + l15]      = f2bf(oacc[0][reg]);
            attn_out[rowb + 16 + l15] = f2bf(oacc[1][reg]);
            if (l15 == 0)
                Zp[((size_t)bm * 6 + cam) * HW + q] = zp[reg];
        }
    }
}

// ---------------------------------------------------------------------------
// LayerNorm over 1536 (bf16 in) + fused joint-softmax normalization -> bf16.
// ---------------------------------------------------------------------------
__global__ __launch_bounds__(256) void ln_pre_kernel(
    const short* __restrict__ xin, short* __restrict__ lnbf,
    const float* __restrict__ Zp,
    const float* __restrict__ g, const float* __restrict__ bt)
{
    const int row = blockIdx.x;
    const int tid = threadIdx.x;
    const int b = row / 2500, q = row % 2500;
    __shared__ float zinv[8];
    if (tid < 8) {
        float z = 0.f;
#pragma unroll
        for (int cam = 0; cam < 6; cam++)
            z += Zp[((size_t)(b * 8 + tid) * 6 + cam) * HW + q];
        zinv[tid] = 1.f / z;
    }
    __syncthreads();
    const short* p = xin + (size_t)row * NDIM;
    float v[6];
    float s = 0.f, ss = 0.f;
#pragma unroll
    for (int i = 0; i < 6; i++) {
        int c = tid + i * 256;
        v[i] = bf2f(p[c]) * zinv[(c >> 5) & 7];
        s += v[i]; ss += v[i] * v[i];
    }
    __shared__ float rs[4], rss[4];
    int lane = tid & 63, wid = tid >> 6;
#pragma unroll
    for (int o = 32; o > 0; o >>= 1) { s += __shfl_down(s, o); ss += __shfl_down(ss, o); }
    if (lane == 0) { rs[wid] = s; rss[wid] = ss; }
    __syncthreads();
    s = rs[0] + rs[1] + rs[2] + rs[3];
    ss = rss[0] + rss[1] + rss[2] + rss[3];
    float mu = s * (1.f / NDIM);
    float var = ss * (1.f / NDIM) - mu * mu;
    float inv = rsqrtf(var + 1e-5f);
#pragma unroll
    for (int i = 0; i < 6; i++) {
        int c = tid + i * 256;
        lnbf[(size_t)row * NDIM + c] = f2bf((v[i] - mu) * inv * g[c] + bt[c]);
    }
}

// ---------------------------------------------------------------------------
// final2 (as R7): coalesced transpose store.
// ---------------------------------------------------------------------------
__global__ __launch_bounds__(256) void final_kernel2(
    const float* __restrict__ x, const float* __restrict__ y2,
    const float* __restrict__ g, const float* __restrict__ bt,
    float* __restrict__ out)
{
    __shared__ float T[256][33];
    __shared__ float ps[32][8], pss[32][8];
    __shared__ float mu_s[32], inv_s[32];
    const int tid = threadIdx.x;
    const int rl = tid & 31, seg = tid >> 5;
    const int r0 = blockIdx.x * 32;
    const int row = r0 + rl;
    const bool ok = row < 5000;

    float4 yv[8];
    float s = 0.f, ss = 0.f;
    if (ok) {
        const float4* yp = (const float4*)(y2 + (size_t)row * DIM + seg * 32);
#pragma unroll
        for (int j = 0; j < 8; j++) {
            yv[j] = yp[j];
            s += yv[j].x + yv[j].y + yv[j].z + yv[j].w;
            ss += yv[j].x * yv[j].x + yv[j].y * yv[j].y
                + yv[j].z * yv[j].z + yv[j].w * yv[j].w;
        }
    } else {
#pragma unroll
        for (int j = 0; j < 8; j++) yv[j] = (float4){0, 0, 0, 0};
    }
    ps[rl][seg] = s; pss[rl][seg] = ss;
    __syncthreads();
    if (tid < 32) {
        float a = 0.f, b2 = 0.f;
#pragma unroll
        for (int j = 0; j < 8; j++) { a += ps[tid][j]; b2 += pss[tid][j]; }
        float mu = a * (1.f / DIM);
        float var = b2 * (1.f / DIM) - mu * mu;
        mu_s[tid] = mu;
        inv_s[tid] = rsqrtf(var + 1e-5f);
    }
    __syncthreads();
    if (ok) {
        float mu = mu_s[rl], inv = inv_s[rl];
        const float4* xp = (const float4*)(x + (size_t)row * DIM + seg * 32);
#pragma unroll
        for (int j = 0; j < 8; j++) {
            float4 xv = xp[j];
            int c = seg * 32 + j * 4;
            T[c + 0][rl] = xv.x + (yv[j].x - mu) * inv * g[c + 0] + bt[c + 0];
            T[c + 1][rl] = xv.y + (yv[j].y - mu) * inv * g[c + 1] + bt[c + 1];
            T[c + 2][rl] = xv.z + (yv[j].z - mu) * inv * g[c + 2] + bt[c + 2];
            T[c + 3][rl] = xv.w + (yv[j].w - mu) * inv * g[c + 3] + bt[c + 3];
        }
    }
    __syncthreads();
    const int w = tid >> 6, lane = tid & 63;
    const int hl = lane & 31, ch = lane >> 5;
    const int rr = r0 + hl;
    if (rr < 5000) {
        int b = rr / 2500, hw = rr % 2500;
        size_t obase = (size_t)b * 640000 + hw;
#pragma unroll
        for (int it = 0; it < 32; it++) {
            int c = it * 8 + w * 2 + ch;
            out[obase + (size_t)c * 2500] = T[c][hl];
        }
    }
}

// ---------------------------------------------------------------------------
extern "C" void kernel_launch(void* const* d_in, const int* in_sizes, int n_in,
                              void* d_out, int out_size, void* d_ws, size_t ws_size,
                              hipStream_t stream)
{
    const float* q     = (const float*)d_in[0];
    const float* k     = (const float*)d_in[1];
    const float* v     = (const float*)d_in[2];
    const float* Wq    = (const float*)d_in[3];
    const float* bq    = (const float*)d_in[4];
    const float* Wk    = (const float*)d_in[5];
    const float* bk    = (const float*)d_in[6];
    const float* Wv    = (const float*)d_in[7];
    const float* bv    = (const float*)d_in[8];
    const float* Wproj = (const float*)d_in[9];
    const float* bproj = (const float*)d_in[10];
    const float* Waddq = (const float*)d_in[11];
    const float* baddq = (const float*)d_in[12];
    const float* W1    = (const float*)d_in[13];
    const float* b1    = (const float*)d_in[14];
    const float* W2    = (const float*)d_in[15];
    const float* b2    = (const float*)d_in[16];
    const float* g_pre = (const float*)d_in[17];
    const float* b_pre = (const float*)d_in[18];
    const float* g_nrm = (const float*)d_in[19];
    const float* b_nrm = (const float*)d_in[20];
    float* out = (float*)d_out;

    // workspace layout (float-unit offsets)
    float* ws = (float*)d_ws;
    short* qf_a   = (short*)(ws);             // [0, 3.84M)
    short* lnbf   = (short*)(ws);             //   alias after attn
    short* qbf    = (short*)(ws + 3840000);   // [3.84M, 7.68M)
    short* kf_a   = (short*)(ws + 7680000);   // [7.68M, 8.64M)
    short* kpbf   = (short*)(ws + 8640000);   // [8.64M, 9.6M)
    short* vf_a   = (short*)(ws + 9600000);   // [9.6M, 10.56M)
    short* vpbf   = (short*)(ws + 10560000);  // [10.56M, 11.52M)
    float* add_q  = ws + 11520000;            // [11.52M, 12.8M)
    short* attn_o = (short*)(ws + 12800000);  // bf16 now: [12.8M, 16.64M)
    short* xbf    = (short*)(ws + 12800000);  //   alias: live only after ln_pre
    short* h1bf   = (short*)(ws + 13440000);  //   alias: [13.44M, 14.72M)
    float* x      = ws + 20480000;            // [20.48M, 21.76M)
    float* Zp     = ws + 21760000;            // [21.76M, 22M)
    short* eW     = (short*)(ws + 22000000);
    short* Wq_t    = eW;
    short* Wk_t    = eW + 65536;
    short* Wv_t    = eW + 131072;
    short* Waddq_t = eW + 196608;
    short* lW     = (short*)(ws + 22295000);
    short* Wproj_t = lW;
    short* W1_t    = lW + 393216;
    short* W2_t    = lW + 524288;
    float* y2     = ws + 22625000;            // [22.62M, 23.9M)

    dim3 blk(256);

    // 1) all conversion work in one launch
    {
        WArgs wa;
        wa.j[0] = {Wq,    Wq_t,    256,  256};
        wa.j[1] = {Wk,    Wk_t,    256,  256};
        wa.j[2] = {Wv,    Wv_t,    256,  256};
        wa.j[3] = {Waddq, Waddq_t, 1536, 256};
        wa.j[4] = {Wproj, Wproj_t, 1536, 256};
        wa.j[5] = {W1,    W1_t,    256,  512};
        wa.j[6] = {W2,    W2_t,    512,  256};
        prep_all<<<dim3(12640), blk, 0, stream>>>(q, k, v, qbf, kpbf, vpbf, wa);
    }
    // 2) all input-side GEMMs in one launch (BM=128)
    {
        GArgs ga;
        ga.j[0] = {qbf,  Wq_t,    bq,    qf_a, nullptr, 30000, 256,  235, 0};
        ga.j[1] = {kpbf, Wk_t,    bk,    kf_a, nullptr, 7500,  256,  59,  0};
        ga.j[2] = {vpbf, Wv_t,    bv,    vf_a, nullptr, 7500,  256,  59,  0};
        ga.j[3] = {qbf,  Waddq_t, baddq, nullptr, add_q, 5000, 1536, 40,  1};
        gemm_in<<<dim3(4, 235, 4), blk, 0, stream>>>(ga);
    }
    // 3) attention (bf16 out)
    attn_mfma<<<dim3(40, 16, 6), blk, 0, stream>>>(qf_a, kf_a, vf_a, attn_o, Zp);
    // 4) LN(1536) + softmax-normalize -> bf16 (into dead qf_a region)
    ln_pre_kernel<<<dim3(5000), blk, 0, stream>>>(attn_o, lnbf, Zp, g_pre, b_pre);
    // 5) x = ln @ Wproj + bproj + add_q  (fp32 x + bf16 xbf)
    mgemm_bf<2, 1, 1><<<dim3(4, 40), blk, 0, stream>>>(
        lnbf, Wproj_t, bproj, add_q, x, xbf, 5000, 256, 1536);
    // 6) h1 = gelu(x @ W1 + b1) -> bf16
    mgemm_bf<1, 0, 1><<<dim3(8, 40), blk, 0, stream>>>(
        xbf, W1_t, b1, nullptr, nullptr, h1bf, 5000, 512, 256);
    // 7) y2 = h1 @ W2 + b2 -> fp32
    mgemm_bf<0, 1, 0><<<dim3(4, 40), blk, 0, stream>>>(
        h1bf, W2_t, b2, nullptr, y2, nullptr, 5000, 256, 512);
    // 8) out = transpose(x + LN256(y2)) — coalesced
    final_kernel2<<<dim3(157), blk, 0, stream>>>(x, y2, g_nrm, b_nrm, out);
}